// Round 3
// baseline (1862.345 us; speedup 1.0000x reference)
//
#include <hip/hip_runtime.h>
#include <math.h>

#define NNODES 100000
#define NEDGES 1600000
#define HF 64

// ---- order-preserving float<->uint key for atomicMax-based segment max ----
__device__ __forceinline__ unsigned fkey(float f) {
    unsigned u = __float_as_uint(f);
    return (u & 0x80000000u) ? ~u : (u | 0x80000000u);
}
__device__ __forceinline__ float funkey(unsigned k) {
    unsigned u = (k & 0x80000000u) ? (k ^ 0x80000000u) : ~k;
    return __uint_as_float(u);
}

// ---- feat = x @ W^T ; el = feat@al ; er = feat@ar ----
// one row per wave, lane = output column. W staged transposed in LDS, stride 65
// (conflict-free on both staging write and inner-loop read).
template <int K>
__global__ __launch_bounds__(256) void gemm_el_er(
    const float* __restrict__ x, const float* __restrict__ W,
    const float* __restrict__ al, const float* __restrict__ ar,
    float* __restrict__ feat, float* __restrict__ el, float* __restrict__ er,
    int n)
{
    __shared__ float wt[K * 65];
    const int tid = threadIdx.x;
    // coalesced read of W [64][K] row-major; transposed write into LDS
    for (int i = tid; i < K * HF; i += 256) {
        int c = i / K;      // output column (W row)
        int k = i % K;      // k index
        wt[k * 65 + c] = W[i];
    }
    __syncthreads();

    const int lane = tid & 63;
    const int wave = tid >> 6;
    const float ral = al[lane];
    const float rar = ar[lane];

    const int row = blockIdx.x * 4 + wave;
    if (row >= n) return;

    const float4* xr = (const float4*)(x + (size_t)row * K);
    float acc = 0.f;
#pragma unroll
    for (int k4 = 0; k4 < K / 4; ++k4) {
        float4 f = xr[k4];          // wave-uniform address -> broadcast
        int kb = k4 * 4;
        acc += f.x * wt[(kb + 0) * 65 + lane];
        acc += f.y * wt[(kb + 1) * 65 + lane];
        acc += f.z * wt[(kb + 2) * 65 + lane];
        acc += f.w * wt[(kb + 3) * 65 + lane];
    }
    feat[(size_t)row * HF + lane] = acc;

    float vl = acc * ral;
    float vr = acc * rar;
#pragma unroll
    for (int off = 32; off >= 1; off >>= 1) {
        vl += __shfl_xor(vl, off);
        vr += __shfl_xor(vr, off);
    }
    if (lane == 0) { el[row] = vl; er[row] = vr; }
}

// ---- pass 1: e = leaky_relu(el[src]+er[dst]); segment max over dst ----
__global__ __launch_bounds__(256) void edge_max(
    const int* __restrict__ src, const int* __restrict__ dst,
    const float* __restrict__ el, const float* __restrict__ er,
    float* __restrict__ ebuf, unsigned* __restrict__ mkeys, int E)
{
    int i = blockIdx.x * 256 + threadIdx.x;
    if (i >= E) return;
    float e = el[src[i]] + er[dst[i]];
    e = (e >= 0.f) ? e : 0.2f * e;
    ebuf[i] = e;
    atomicMax(&mkeys[dst[i]], fkey(e));
}

// ---- pass 2: ee = exp(e - m[dst]); segment sum over dst ----
__global__ __launch_bounds__(256) void edge_expsum(
    const int* __restrict__ dst, float* __restrict__ ebuf,
    const unsigned* __restrict__ mkeys, float* __restrict__ denom, int E)
{
    int i = blockIdx.x * 256 + threadIdx.x;
    if (i >= E) return;
    int d = dst[i];
    float m = funkey(mkeys[d]);
    float ee = __expf(ebuf[i] - m);
    ebuf[i] = ee;
    atomicAdd(&denom[d], ee);
}

// ---- pass 3: out[dst] += (ee/denom[dst]) * feat[src] ; one edge per wave ----
__global__ __launch_bounds__(256) void edge_agg(
    const int* __restrict__ src, const int* __restrict__ dst,
    const float* __restrict__ ebuf, const float* __restrict__ denom,
    const float* __restrict__ feat, float* __restrict__ out, int E)
{
    int e = blockIdx.x * 4 + (threadIdx.x >> 6);
    if (e >= E) return;
    int lane = threadIdx.x & 63;
    int s = src[e];
    int d = dst[e];
    float alpha = ebuf[e] / denom[d];
    float v = feat[(size_t)s * HF + lane] * alpha;
    atomicAdd(&out[(size_t)d * HF + lane], v);
}

// ---- h = relu(agg + b) (in-place ok) ----
__global__ __launch_bounds__(256) void finalize_k(
    const float* __restrict__ agg, const float* __restrict__ b,
    float* __restrict__ h, int n)
{
    int i = blockIdx.x * 256 + threadIdx.x;
    if (i >= n * HF) return;
    h[i] = fmaxf(agg[i] + b[i & 63], 0.f);
}

extern "C" void kernel_launch(void* const* d_in, const int* in_sizes, int n_in,
                              void* d_out, int out_size, void* d_ws, size_t ws_size,
                              hipStream_t stream) {
    const int N = NNODES;
    const int E = NEDGES;

    const float* in_feat = (const float*)d_in[0];
    const float* W1 = (const float*)d_in[1];
    const float* al1 = (const float*)d_in[2];
    const float* ar1 = (const float*)d_in[3];
    const float* b1 = (const float*)d_in[4];
    const float* W2 = (const float*)d_in[5];
    const float* al2 = (const float*)d_in[6];
    const float* ar2 = (const float*)d_in[7];
    const float* b2 = (const float*)d_in[8];
    const float* W3 = (const float*)d_in[9];
    const float* al3 = (const float*)d_in[10];
    const float* ar3 = (const float*)d_in[11];
    const float* b3 = (const float*)d_in[12];
    const int* src = (const int*)d_in[13];
    const int* dst = (const int*)d_in[14];

    // workspace layout (floats)
    float* ws = (float*)d_ws;
    float* feat = ws;                       // N*64
    float* h1   = feat + (size_t)N * HF;    // N*64
    float* h2   = h1 + (size_t)N * HF;      // N*64
    float* ebuf = h2 + (size_t)N * HF;      // E
    float* el   = ebuf + (size_t)E;         // N
    float* er   = el + N;                   // N
    float* denom = er + N;                  // N
    unsigned* mkeys = (unsigned*)(denom + N); // N

    const int gRows = (N + 3) / 4;
    const int gEdgeT = (E + 255) / 256;
    const int gEdgeW = (E + 3) / 4;
    const int gElem = (N * HF + 255) / 256;

    // ---------- layer 1 (K=128) ----------
    hipMemsetAsync(mkeys, 0, (size_t)N * 4, stream);
    hipMemsetAsync(denom, 0, (size_t)N * 4, stream);
    hipMemsetAsync(h1, 0, (size_t)N * HF * 4, stream);
    gemm_el_er<128><<<gRows, 256, 0, stream>>>(in_feat, W1, al1, ar1, feat, el, er, N);
    edge_max<<<gEdgeT, 256, 0, stream>>>(src, dst, el, er, ebuf, mkeys, E);
    edge_expsum<<<gEdgeT, 256, 0, stream>>>(dst, ebuf, mkeys, denom, E);
    edge_agg<<<gEdgeW, 256, 0, stream>>>(src, dst, ebuf, denom, feat, h1, E);
    finalize_k<<<gElem, 256, 0, stream>>>(h1, b1, h1, N);

    // ---------- layer 2 (K=64) ----------
    hipMemsetAsync(mkeys, 0, (size_t)N * 4, stream);
    hipMemsetAsync(denom, 0, (size_t)N * 4, stream);
    hipMemsetAsync(h2, 0, (size_t)N * HF * 4, stream);
    gemm_el_er<64><<<gRows, 256, 0, stream>>>(h1, W2, al2, ar2, feat, el, er, N);
    edge_max<<<gEdgeT, 256, 0, stream>>>(src, dst, el, er, ebuf, mkeys, E);
    edge_expsum<<<gEdgeT, 256, 0, stream>>>(dst, ebuf, mkeys, denom, E);
    edge_agg<<<gEdgeW, 256, 0, stream>>>(src, dst, ebuf, denom, feat, h2, E);
    finalize_k<<<gElem, 256, 0, stream>>>(h2, b2, h2, N);

    // ---------- layer 3 (K=64), agg directly into d_out ----------
    float* out = (float*)d_out;
    hipMemsetAsync(mkeys, 0, (size_t)N * 4, stream);
    hipMemsetAsync(denom, 0, (size_t)N * 4, stream);
    hipMemsetAsync(out, 0, (size_t)N * HF * 4, stream);
    gemm_el_er<64><<<gRows, 256, 0, stream>>>(h2, W3, al3, ar3, feat, el, er, N);
    edge_max<<<gEdgeT, 256, 0, stream>>>(src, dst, el, er, ebuf, mkeys, E);
    edge_expsum<<<gEdgeT, 256, 0, stream>>>(dst, ebuf, mkeys, denom, E);
    edge_agg<<<gEdgeW, 256, 0, stream>>>(src, dst, ebuf, denom, feat, out, E);
    finalize_k<<<gElem, 256, 0, stream>>>(out, b3, out, N);
}

// Round 4
// 801.458 us; speedup vs baseline: 2.3237x; 2.3237x over previous
//
#include <hip/hip_runtime.h>
#include <math.h>

#define NNODES 100000
#define NEDGES 1600000
#define HF 64

// ======================= CSR build (per call, deterministic work) =========
__global__ __launch_bounds__(256) void k_hist(
    const int* __restrict__ dst, int* __restrict__ deg, int E)
{
    int i = blockIdx.x * 256 + threadIdx.x;
    if (i < E) atomicAdd(&deg[dst[i]], 1);
}

// per-block (1024 elems) exclusive scan -> cur[], block sums -> bsum[]
__global__ __launch_bounds__(256) void k_scan1(
    const int* __restrict__ deg, int* __restrict__ cur, int* __restrict__ bsum, int n)
{
    __shared__ int s[256];
    const int tid = threadIdx.x;
    const int gbase = blockIdx.x * 1024 + tid * 4;
    int v[4];
#pragma unroll
    for (int q = 0; q < 4; ++q) {
        int idx = gbase + q;
        v[q] = (idx < n) ? deg[idx] : 0;
    }
    int tsum = v[0] + v[1] + v[2] + v[3];
    s[tid] = tsum;
    __syncthreads();
    for (int off = 1; off < 256; off <<= 1) {
        int t = (tid >= off) ? s[tid - off] : 0;
        __syncthreads();
        s[tid] += t;
        __syncthreads();
    }
    int run = s[tid] - tsum;   // exclusive prefix of this thread's 4
#pragma unroll
    for (int q = 0; q < 4; ++q) {
        int idx = gbase + q;
        if (idx < n) cur[idx] = run;
        run += v[q];
    }
    if (tid == 255) bsum[blockIdx.x] = s[255];
}

// single-block exclusive scan of nb (<=128) block sums, in place
__global__ __launch_bounds__(128) void k_scan2(int* __restrict__ bsum, int nb)
{
    __shared__ int s[128];
    const int tid = threadIdx.x;
    int own = (tid < nb) ? bsum[tid] : 0;
    s[tid] = own;
    __syncthreads();
    for (int off = 1; off < 128; off <<= 1) {
        int t = (tid >= off) ? s[tid - off] : 0;
        __syncthreads();
        s[tid] += t;
        __syncthreads();
    }
    if (tid < nb) bsum[tid] = s[tid] - own;
}

__global__ __launch_bounds__(256) void k_scan3(
    int* __restrict__ cur, const int* __restrict__ bsum, int n)
{
    int i = blockIdx.x * 256 + threadIdx.x;
    if (i < n) cur[i] += bsum[i >> 10];
}

// scatter src ids into dst-segment order; cur ends at rowptr[d]+deg[d]
__global__ __launch_bounds__(256) void k_scatter(
    const int* __restrict__ src, const int* __restrict__ dst,
    int* __restrict__ cur, int* __restrict__ esrc, int E)
{
    int i = blockIdx.x * 256 + threadIdx.x;
    if (i >= E) return;
    int p = atomicAdd(&cur[dst[i]], 1);
    esrc[p] = src[i];
}

// ======================= feat = x@W^T ; el = feat@al ; er = feat@ar =======
// one row per wave, lane = output column; W transposed in LDS (stride 65).
template <int K>
__global__ __launch_bounds__(256) void gemm_el_er(
    const float* __restrict__ x, const float* __restrict__ W,
    const float* __restrict__ al, const float* __restrict__ ar,
    float* __restrict__ feat, float* __restrict__ el, float* __restrict__ er,
    int n)
{
    __shared__ float wt[K * 65];
    const int tid = threadIdx.x;
    for (int i = tid; i < K * HF; i += 256) {
        int c = i / K;
        int k = i % K;
        wt[k * 65 + c] = W[i];
    }
    __syncthreads();

    const int lane = tid & 63;
    const int wave = tid >> 6;
    const float ral = al[lane];
    const float rar = ar[lane];

    const int row = blockIdx.x * 4 + wave;
    if (row >= n) return;

    const float4* xr = (const float4*)(x + (size_t)row * K);
    float acc = 0.f;
#pragma unroll
    for (int k4 = 0; k4 < K / 4; ++k4) {
        float4 f = xr[k4];
        int kb = k4 * 4;
        acc += f.x * wt[(kb + 0) * 65 + lane];
        acc += f.y * wt[(kb + 1) * 65 + lane];
        acc += f.z * wt[(kb + 2) * 65 + lane];
        acc += f.w * wt[(kb + 3) * 65 + lane];
    }
    feat[(size_t)row * HF + lane] = acc;

    float vl = acc * ral;
    float vr = acc * rar;
#pragma unroll
    for (int off = 32; off >= 1; off >>= 1) {
        vl += __shfl_xor(vl, off);
        vr += __shfl_xor(vr, off);
    }
    if (lane == 0) { el[row] = vl; er[row] = vr; }
}

// ======================= fused per-node softmax-aggregate =================
// one wave per dst node. cur[d] = rowptr[d]+deg[d] after scatter.
__global__ __launch_bounds__(256) void node_agg(
    const int* __restrict__ cur, const int* __restrict__ deg,
    const int* __restrict__ esrc,
    const float* __restrict__ el, const float* __restrict__ er,
    const float* __restrict__ feat, const float* __restrict__ bias,
    float* __restrict__ out, int n)
{
    const int node = blockIdx.x * 4 + (threadIdx.x >> 6);
    if (node >= n) return;
    const int lane = threadIdx.x & 63;

    const int dg = deg[node];
    const int base = cur[node] - dg;
    const float erd = er[node];

    // phase 1: lane-parallel leaky-relu + max; cache first chunk in regs
    float m = -INFINITY;
    int sreg = 0;
    float ereg = 0.f;
    for (int j = lane; j < dg; j += 64) {
        int s = esrc[base + j];
        float e = el[s] + erd;
        e = (e >= 0.f) ? e : 0.2f * e;
        if (j < 64) { sreg = s; ereg = e; }
        m = fmaxf(m, e);
    }
#pragma unroll
    for (int off = 32; off >= 1; off >>= 1)
        m = fmaxf(m, __shfl_xor(m, off));

    // phase 2: acc = sum ee * feat[src][lane]; den = sum ee
    float acc = 0.f, den = 0.f;
    if (dg <= 64) {
        for (int j = 0; j < dg; ++j) {
            int   s = __shfl(sreg, j);
            float e = __shfl(ereg, j);
            float ee = __expf(e - m);
            den += ee;
            acc += ee * feat[(size_t)s * HF + lane];
        }
    } else {
        for (int j = 0; j < dg; ++j) {
            int s = esrc[base + j];
            float e = el[s] + erd;
            e = (e >= 0.f) ? e : 0.2f * e;
            float ee = __expf(e - m);
            den += ee;
            acc += ee * feat[(size_t)s * HF + lane];
        }
    }

    float o = (dg > 0) ? (acc / den) : 0.f;
    out[(size_t)node * HF + lane] = fmaxf(o + bias[lane], 0.f);
}

extern "C" void kernel_launch(void* const* d_in, const int* in_sizes, int n_in,
                              void* d_out, int out_size, void* d_ws, size_t ws_size,
                              hipStream_t stream) {
    const int N = NNODES;
    const int E = NEDGES;

    const float* in_feat = (const float*)d_in[0];
    const float* W1 = (const float*)d_in[1];
    const float* al1 = (const float*)d_in[2];
    const float* ar1 = (const float*)d_in[3];
    const float* b1 = (const float*)d_in[4];
    const float* W2 = (const float*)d_in[5];
    const float* al2 = (const float*)d_in[6];
    const float* ar2 = (const float*)d_in[7];
    const float* b2 = (const float*)d_in[8];
    const float* W3 = (const float*)d_in[9];
    const float* al3 = (const float*)d_in[10];
    const float* ar3 = (const float*)d_in[11];
    const float* b3 = (const float*)d_in[12];
    const int* src = (const int*)d_in[13];
    const int* dst = (const int*)d_in[14];

    // workspace layout (4B units); total ~21.2M elems (~85MB), same as before
    float* ws = (float*)d_ws;
    float* feat = ws;                          // N*64
    float* h1   = feat + (size_t)N * HF;       // N*64
    float* h2   = h1 + (size_t)N * HF;         // N*64
    float* el   = h2 + (size_t)N * HF;         // N
    float* er   = el + N;                      // N
    int* deg    = (int*)(er + N);              // N
    int* cur    = deg + N;                     // N
    int* bsum   = cur + N;                     // 128 (pad 256)
    int* esrc   = bsum + 256;                  // E

    const int NB1024 = (N + 1023) / 1024;      // 98
    const int gEdge = (E + 255) / 256;
    const int gNode4 = (N + 3) / 4;
    const int gN256 = (N + 255) / 256;

    // ---- CSR build (graph is identical for all 3 layers) ----
    hipMemsetAsync(deg, 0, (size_t)N * 4, stream);
    k_hist<<<gEdge, 256, 0, stream>>>(dst, deg, E);
    k_scan1<<<NB1024, 256, 0, stream>>>(deg, cur, bsum, N);
    k_scan2<<<1, 128, 0, stream>>>(bsum, NB1024);
    k_scan3<<<gN256, 256, 0, stream>>>(cur, bsum, N);
    k_scatter<<<gEdge, 256, 0, stream>>>(src, dst, cur, esrc, E);

    float* out = (float*)d_out;

    // ---- layer 1 (K=128) ----
    gemm_el_er<128><<<gNode4, 256, 0, stream>>>(in_feat, W1, al1, ar1, feat, el, er, N);
    node_agg<<<gNode4, 256, 0, stream>>>(cur, deg, esrc, el, er, feat, b1, h1, N);

    // ---- layer 2 (K=64) ----
    gemm_el_er<64><<<gNode4, 256, 0, stream>>>(h1, W2, al2, ar2, feat, el, er, N);
    node_agg<<<gNode4, 256, 0, stream>>>(cur, deg, esrc, el, er, feat, b2, h2, N);

    // ---- layer 3 (K=64) ----
    gemm_el_er<64><<<gNode4, 256, 0, stream>>>(h2, W3, al3, ar3, feat, el, er, N);
    node_agg<<<gNode4, 256, 0, stream>>>(cur, deg, esrc, el, er, feat, b3, out, N);
}

// Round 5
// 597.987 us; speedup vs baseline: 3.1144x; 1.3403x over previous
//
#include <hip/hip_runtime.h>
#include <math.h>

#define NNODES 100000
#define NEDGES 1600000
#define HF 64

// ======================= CSR build (per call, deterministic work) =========
__global__ __launch_bounds__(256) void k_hist(
    const int* __restrict__ dst, int* __restrict__ deg, int E)
{
    int i = blockIdx.x * 256 + threadIdx.x;
    if (i < E) atomicAdd(&deg[dst[i]], 1);
}

__global__ __launch_bounds__(256) void k_scan1(
    const int* __restrict__ deg, int* __restrict__ cur, int* __restrict__ bsum, int n)
{
    __shared__ int s[256];
    const int tid = threadIdx.x;
    const int gbase = blockIdx.x * 1024 + tid * 4;
    int v[4];
#pragma unroll
    for (int q = 0; q < 4; ++q) {
        int idx = gbase + q;
        v[q] = (idx < n) ? deg[idx] : 0;
    }
    int tsum = v[0] + v[1] + v[2] + v[3];
    s[tid] = tsum;
    __syncthreads();
    for (int off = 1; off < 256; off <<= 1) {
        int t = (tid >= off) ? s[tid - off] : 0;
        __syncthreads();
        s[tid] += t;
        __syncthreads();
    }
    int run = s[tid] - tsum;
#pragma unroll
    for (int q = 0; q < 4; ++q) {
        int idx = gbase + q;
        if (idx < n) cur[idx] = run;
        run += v[q];
    }
    if (tid == 255) bsum[blockIdx.x] = s[255];
}

__global__ __launch_bounds__(128) void k_scan2(int* __restrict__ bsum, int nb)
{
    __shared__ int s[128];
    const int tid = threadIdx.x;
    int own = (tid < nb) ? bsum[tid] : 0;
    s[tid] = own;
    __syncthreads();
    for (int off = 1; off < 128; off <<= 1) {
        int t = (tid >= off) ? s[tid - off] : 0;
        __syncthreads();
        s[tid] += t;
        __syncthreads();
    }
    if (tid < nb) bsum[tid] = s[tid] - own;
}

__global__ __launch_bounds__(256) void k_scan3(
    int* __restrict__ cur, const int* __restrict__ bsum, int n)
{
    int i = blockIdx.x * 256 + threadIdx.x;
    if (i < n) cur[i] += bsum[i >> 10];
}

__global__ __launch_bounds__(256) void k_scatter(
    const int* __restrict__ src, const int* __restrict__ dst,
    int* __restrict__ cur, int* __restrict__ esrc, int E)
{
    int i = blockIdx.x * 256 + threadIdx.x;
    if (i >= E) return;
    int p = atomicAdd(&cur[dst[i]], 1);
    esrc[p] = src[i];
}

// ======================= tiled GEMM: feat = x@W^T, el, er ================
// block = 256 threads -> 128-row x 64-col output tile; thread = 8x4 regs.
// tx = tid&15 (col group, 4 cols), ty = tid>>4 (row group, 8 rows).
// LDS: x transposed chunk xs[k][row] (stride 132), W transposed wt[k][col]
// (stride 68) -> b128 reads, conflict-free / 2-way (free).
template <int K>
__global__ __launch_bounds__(256) void gemm_tile(
    const float* __restrict__ x, const float* __restrict__ W,
    const float* __restrict__ al, const float* __restrict__ ar,
    float* __restrict__ feat, float* __restrict__ el, float* __restrict__ er,
    int n)
{
    constexpr int KS = 32;
    __shared__ float xs[KS][132];   // 132*4=528B stride: 16B-aligned rows
    __shared__ float wt[KS][68];    // 68*4=272B stride: 16B-aligned rows

    const int tid = threadIdx.x;
    const int tx = tid & 15;
    const int ty = tid >> 4;
    const int row0 = blockIdx.x * 128;

    float acc[8][4];
#pragma unroll
    for (int i = 0; i < 8; ++i)
#pragma unroll
        for (int j = 0; j < 4; ++j) acc[i][j] = 0.f;

    for (int ks = 0; ks < K; ks += KS) {
        if (ks) __syncthreads();
        // stage x chunk: 128 rows x 32 k -> 1024 float4, 4 per thread
#pragma unroll
        for (int jj = 0; jj < 4; ++jj) {
            int j = tid + jj * 256;
            int r = j >> 3;          // 0..127
            int k4 = j & 7;          // 0..7
            int gr = row0 + r;
            float4 v = make_float4(0.f, 0.f, 0.f, 0.f);
            if (gr < n) v = *(const float4*)(x + (size_t)gr * K + ks + 4 * k4);
            xs[4 * k4 + 0][r] = v.x;
            xs[4 * k4 + 1][r] = v.y;
            xs[4 * k4 + 2][r] = v.z;
            xs[4 * k4 + 3][r] = v.w;
        }
        // stage W chunk: wt[k][c] = W[c*K + ks + k]; 64 cols x 32 k -> 512 f4
#pragma unroll
        for (int jj = 0; jj < 2; ++jj) {
            int j = tid + jj * 256;
            int c = j >> 3;          // 0..63
            int k4 = j & 7;
            float4 v = *(const float4*)(W + (size_t)c * K + ks + 4 * k4);
            wt[4 * k4 + 0][c] = v.x;
            wt[4 * k4 + 1][c] = v.y;
            wt[4 * k4 + 2][c] = v.z;
            wt[4 * k4 + 3][c] = v.w;
        }
        __syncthreads();

#pragma unroll 8
        for (int k = 0; k < KS; ++k) {
            float4 a0 = *(const float4*)&xs[k][8 * ty + 0];
            float4 a1 = *(const float4*)&xs[k][8 * ty + 4];
            float4 b  = *(const float4*)&wt[k][4 * tx];
            float ar_[8] = {a0.x, a0.y, a0.z, a0.w, a1.x, a1.y, a1.z, a1.w};
            float bc[4] = {b.x, b.y, b.z, b.w};
#pragma unroll
            for (int i = 0; i < 8; ++i)
#pragma unroll
                for (int j = 0; j < 4; ++j)
                    acc[i][j] += ar_[i] * bc[j];
        }
    }

    // epilogue: write feat, reduce el/er across tx (16 lanes of the wave)
    const float4 ald = *(const float4*)(al + 4 * tx);
    const float4 ard = *(const float4*)(ar + 4 * tx);
#pragma unroll
    for (int i = 0; i < 8; ++i) {
        int row = row0 + 8 * ty + i;
        float pl = acc[i][0] * ald.x + acc[i][1] * ald.y +
                   acc[i][2] * ald.z + acc[i][3] * ald.w;
        float pr = acc[i][0] * ard.x + acc[i][1] * ard.y +
                   acc[i][2] * ard.z + acc[i][3] * ard.w;
#pragma unroll
        for (int off = 8; off >= 1; off >>= 1) {
            pl += __shfl_xor(pl, off);
            pr += __shfl_xor(pr, off);
        }
        if (row < n) {
            float4 st = make_float4(acc[i][0], acc[i][1], acc[i][2], acc[i][3]);
            *(float4*)(feat + (size_t)row * HF + 4 * tx) = st;
            if (tx == 0) { el[row] = pl; er[row] = pr; }
        }
    }
}

// ======================= fused per-node softmax-aggregate =================
__global__ __launch_bounds__(256) void node_agg(
    const int* __restrict__ cur, const int* __restrict__ deg,
    const int* __restrict__ esrc,
    const float* __restrict__ el, const float* __restrict__ er,
    const float* __restrict__ feat, const float* __restrict__ bias,
    float* __restrict__ out, int n)
{
    const int node = blockIdx.x * 4 + (threadIdx.x >> 6);
    if (node >= n) return;
    const int lane = threadIdx.x & 63;

    const int dg = deg[node];
    const int base = cur[node] - dg;
    const float erd = er[node];

    float m = -INFINITY;
    int sreg = 0;
    float ereg = 0.f;
    for (int j = lane; j < dg; j += 64) {
        int s = esrc[base + j];
        float e = el[s] + erd;
        e = (e >= 0.f) ? e : 0.2f * e;
        if (j < 64) { sreg = s; ereg = e; }
        m = fmaxf(m, e);
    }
#pragma unroll
    for (int off = 32; off >= 1; off >>= 1)
        m = fmaxf(m, __shfl_xor(m, off));

    float acc = 0.f, den = 0.f;
    if (dg <= 64) {
        for (int j = 0; j < dg; ++j) {
            int   s = __shfl(sreg, j);
            float e = __shfl(ereg, j);
            float ee = __expf(e - m);
            den += ee;
            acc += ee * feat[(size_t)s * HF + lane];
        }
    } else {
        for (int j = 0; j < dg; ++j) {
            int s = esrc[base + j];
            float e = el[s] + erd;
            e = (e >= 0.f) ? e : 0.2f * e;
            float ee = __expf(e - m);
            den += ee;
            acc += ee * feat[(size_t)s * HF + lane];
        }
    }

    float o = (dg > 0) ? (acc / den) : 0.f;
    out[(size_t)node * HF + lane] = fmaxf(o + bias[lane], 0.f);
}

extern "C" void kernel_launch(void* const* d_in, const int* in_sizes, int n_in,
                              void* d_out, int out_size, void* d_ws, size_t ws_size,
                              hipStream_t stream) {
    const int N = NNODES;
    const int E = NEDGES;

    const float* in_feat = (const float*)d_in[0];
    const float* W1 = (const float*)d_in[1];
    const float* al1 = (const float*)d_in[2];
    const float* ar1 = (const float*)d_in[3];
    const float* b1 = (const float*)d_in[4];
    const float* W2 = (const float*)d_in[5];
    const float* al2 = (const float*)d_in[6];
    const float* ar2 = (const float*)d_in[7];
    const float* b2 = (const float*)d_in[8];
    const float* W3 = (const float*)d_in[9];
    const float* al3 = (const float*)d_in[10];
    const float* ar3 = (const float*)d_in[11];
    const float* b3 = (const float*)d_in[12];
    const int* src = (const int*)d_in[13];
    const int* dst = (const int*)d_in[14];

    float* ws = (float*)d_ws;
    float* feat = ws;                          // N*64
    float* h1   = feat + (size_t)N * HF;       // N*64
    float* h2   = h1 + (size_t)N * HF;         // N*64
    float* el   = h2 + (size_t)N * HF;         // N
    float* er   = el + N;                      // N
    int* deg    = (int*)(er + N);              // N
    int* cur    = deg + N;                     // N
    int* bsum   = cur + N;                     // 128 (pad 256)
    int* esrc   = bsum + 256;                  // E

    const int NB1024 = (N + 1023) / 1024;
    const int gEdge = (E + 255) / 256;
    const int gNode4 = (N + 3) / 4;
    const int gN256 = (N + 255) / 256;
    const int gTile = (N + 127) / 128;

    // ---- CSR build (same graph for all 3 layers) ----
    hipMemsetAsync(deg, 0, (size_t)N * 4, stream);
    k_hist<<<gEdge, 256, 0, stream>>>(dst, deg, E);
    k_scan1<<<NB1024, 256, 0, stream>>>(deg, cur, bsum, N);
    k_scan2<<<1, 128, 0, stream>>>(bsum, NB1024);
    k_scan3<<<gN256, 256, 0, stream>>>(cur, bsum, N);
    k_scatter<<<gEdge, 256, 0, stream>>>(src, dst, cur, esrc, E);

    float* out = (float*)d_out;

    // ---- layer 1 (K=128) ----
    gemm_tile<128><<<gTile, 256, 0, stream>>>(in_feat, W1, al1, ar1, feat, el, er, N);
    node_agg<<<gNode4, 256, 0, stream>>>(cur, deg, esrc, el, er, feat, b1, h1, N);

    // ---- layer 2 (K=64) ----
    gemm_tile<64><<<gTile, 256, 0, stream>>>(h1, W2, al2, ar2, feat, el, er, N);
    node_agg<<<gNode4, 256, 0, stream>>>(cur, deg, esrc, el, er, feat, b2, h2, N);

    // ---- layer 3 (K=64) ----
    gemm_tile<64><<<gTile, 256, 0, stream>>>(h2, W3, al3, ar3, feat, el, er, N);
    node_agg<<<gNode4, 256, 0, stream>>>(cur, deg, esrc, el, er, feat, b3, out, N);
}

// Round 6
// 553.306 us; speedup vs baseline: 3.3659x; 1.0808x over previous
//
#include <hip/hip_runtime.h>
#include <math.h>

#define NNODES 100000
#define NEDGES 1600000
#define HF 64
#define NBUCK_SHIFT 9
#define NBUCK 256   // buckets actually used: (NNODES-1>>9)+1 = 196

// ======================= CSR build =======================================
__global__ __launch_bounds__(256) void k_hist(
    const int* __restrict__ dst, int* __restrict__ deg, int E)
{
    int i = blockIdx.x * 256 + threadIdx.x;
    if (i < E) atomicAdd(&deg[dst[i]], 1);
}

__global__ __launch_bounds__(256) void k_scan1(
    const int* __restrict__ deg, int* __restrict__ cur, int* __restrict__ bsum, int n)
{
    __shared__ int s[256];
    const int tid = threadIdx.x;
    const int gbase = blockIdx.x * 1024 + tid * 4;
    int v[4];
#pragma unroll
    for (int q = 0; q < 4; ++q) {
        int idx = gbase + q;
        v[q] = (idx < n) ? deg[idx] : 0;
    }
    int tsum = v[0] + v[1] + v[2] + v[3];
    s[tid] = tsum;
    __syncthreads();
    for (int off = 1; off < 256; off <<= 1) {
        int t = (tid >= off) ? s[tid - off] : 0;
        __syncthreads();
        s[tid] += t;
        __syncthreads();
    }
    int run = s[tid] - tsum;
#pragma unroll
    for (int q = 0; q < 4; ++q) {
        int idx = gbase + q;
        if (idx < n) cur[idx] = run;
        run += v[q];
    }
    if (tid == 255) bsum[blockIdx.x] = s[255];
}

__global__ __launch_bounds__(128) void k_scan2(int* __restrict__ bsum, int nb)
{
    __shared__ int s[128];
    const int tid = threadIdx.x;
    int own = (tid < nb) ? bsum[tid] : 0;
    s[tid] = own;
    __syncthreads();
    for (int off = 1; off < 128; off <<= 1) {
        int t = (tid >= off) ? s[tid - off] : 0;
        __syncthreads();
        s[tid] += t;
        __syncthreads();
    }
    if (tid < nb) bsum[tid] = s[tid] - own;
}

__global__ __launch_bounds__(256) void k_scan3(
    int* __restrict__ cur, const int* __restrict__ bsum, int n)
{
    int i = blockIdx.x * 256 + threadIdx.x;
    if (i < n) cur[i] += bsum[i >> 10];
}

// gcur[b] = edge-space start of bucket b (= rowptr[b<<9])
__global__ __launch_bounds__(256) void k_bucketinit(
    const int* __restrict__ cur, int* __restrict__ gcur, int n, int E)
{
    int b = threadIdx.x;
    int idx = b << NBUCK_SHIFT;
    gcur[b] = (idx < n) ? cur[idx] : E;
}

// pass 1: partition edges into dst-buckets (locality-friendly writes).
// 256 blocks; per-block LDS histogram -> global run reservation -> scatter.
__global__ __launch_bounds__(256) void k_bucket(
    const int* __restrict__ src, const int* __restrict__ dst,
    int* __restrict__ gcur, int2* __restrict__ ebuf2, int E)
{
    __shared__ int hist[NBUCK];
    const int tid = threadIdx.x;
    const int EPB = (E + 255) / 256;
    const int e0 = blockIdx.x * EPB;
    const int e1 = min(E, e0 + EPB);

    hist[tid] = 0;
    __syncthreads();
    for (int i = e0 + tid; i < e1; i += 256)
        atomicAdd(&hist[dst[i] >> NBUCK_SHIFT], 1);
    __syncthreads();
    int cnt = hist[tid];
    int base = (cnt > 0) ? atomicAdd(&gcur[tid], cnt) : 0;
    __syncthreads();
    hist[tid] = base;          // becomes running cursor for this block's run
    __syncthreads();
    for (int i = e0 + tid; i < e1; i += 256) {
        int d = dst[i];
        int r = atomicAdd(&hist[d >> NBUCK_SHIFT], 1);
        ebuf2[r] = make_int2(src[i], d);
    }
}

// pass 2: bucket-ordered final scatter; cur[d] ends at rowptr[d]+deg[d]
__global__ __launch_bounds__(256) void k_scatter2(
    const int2* __restrict__ ebuf2, int* __restrict__ cur,
    int* __restrict__ esrc, int E)
{
    int i = blockIdx.x * 256 + threadIdx.x;
    if (i >= E) return;
    int2 e = ebuf2[i];
    int p = atomicAdd(&cur[e.y], 1);
    esrc[p] = e.x;
}

// ======================= tiled GEMM: feat = x@W^T, el, er ================
template <int K>
__global__ __launch_bounds__(256) void gemm_tile(
    const float* __restrict__ x, const float* __restrict__ W,
    const float* __restrict__ al, const float* __restrict__ ar,
    float* __restrict__ feat, float* __restrict__ el, float* __restrict__ er,
    int n)
{
    constexpr int KS = 32;
    __shared__ float xs[KS][132];
    __shared__ float wt[KS][68];

    const int tid = threadIdx.x;
    const int tx = tid & 15;
    const int ty = tid >> 4;
    const int row0 = blockIdx.x * 128;

    float acc[8][4];
#pragma unroll
    for (int i = 0; i < 8; ++i)
#pragma unroll
        for (int j = 0; j < 4; ++j) acc[i][j] = 0.f;

    for (int ks = 0; ks < K; ks += KS) {
        if (ks) __syncthreads();
#pragma unroll
        for (int jj = 0; jj < 4; ++jj) {
            int j = tid + jj * 256;
            int r = j >> 3;
            int k4 = j & 7;
            int gr = row0 + r;
            float4 v = make_float4(0.f, 0.f, 0.f, 0.f);
            if (gr < n) v = *(const float4*)(x + (size_t)gr * K + ks + 4 * k4);
            xs[4 * k4 + 0][r] = v.x;
            xs[4 * k4 + 1][r] = v.y;
            xs[4 * k4 + 2][r] = v.z;
            xs[4 * k4 + 3][r] = v.w;
        }
#pragma unroll
        for (int jj = 0; jj < 2; ++jj) {
            int j = tid + jj * 256;
            int c = j >> 3;
            int k4 = j & 7;
            float4 v = *(const float4*)(W + (size_t)c * K + ks + 4 * k4);
            wt[4 * k4 + 0][c] = v.x;
            wt[4 * k4 + 1][c] = v.y;
            wt[4 * k4 + 2][c] = v.z;
            wt[4 * k4 + 3][c] = v.w;
        }
        __syncthreads();

#pragma unroll 8
        for (int k = 0; k < KS; ++k) {
            float4 a0 = *(const float4*)&xs[k][8 * ty + 0];
            float4 a1 = *(const float4*)&xs[k][8 * ty + 4];
            float4 b  = *(const float4*)&wt[k][4 * tx];
            float ar_[8] = {a0.x, a0.y, a0.z, a0.w, a1.x, a1.y, a1.z, a1.w};
            float bc[4] = {b.x, b.y, b.z, b.w};
#pragma unroll
            for (int i = 0; i < 8; ++i)
#pragma unroll
                for (int j = 0; j < 4; ++j)
                    acc[i][j] += ar_[i] * bc[j];
        }
    }

    const float4 ald = *(const float4*)(al + 4 * tx);
    const float4 ard = *(const float4*)(ar + 4 * tx);
#pragma unroll
    for (int i = 0; i < 8; ++i) {
        int row = row0 + 8 * ty + i;
        float pl = acc[i][0] * ald.x + acc[i][1] * ald.y +
                   acc[i][2] * ald.z + acc[i][3] * ald.w;
        float pr = acc[i][0] * ard.x + acc[i][1] * ard.y +
                   acc[i][2] * ard.z + acc[i][3] * ard.w;
#pragma unroll
        for (int off = 8; off >= 1; off >>= 1) {
            pl += __shfl_xor(pl, off);
            pr += __shfl_xor(pr, off);
        }
        if (row < n) {
            float4 st = make_float4(acc[i][0], acc[i][1], acc[i][2], acc[i][3]);
            *(float4*)(feat + (size_t)row * HF + 4 * tx) = st;
            if (tx == 0) { el[row] = pl; er[row] = pr; }
        }
    }
}

// ======================= fused per-node softmax-aggregate =================
__global__ __launch_bounds__(256) void node_agg(
    const int* __restrict__ cur, const int* __restrict__ deg,
    const int* __restrict__ esrc,
    const float* __restrict__ el, const float* __restrict__ er,
    const float* __restrict__ feat, const float* __restrict__ bias,
    float* __restrict__ out, int n)
{
    const int node = blockIdx.x * 4 + (threadIdx.x >> 6);
    if (node >= n) return;
    const int lane = threadIdx.x & 63;

    const int dg = deg[node];
    const int base = cur[node] - dg;
    const float erd = er[node];

    float m = -INFINITY;
    int sreg = 0;
    float ereg = 0.f;
    for (int j = lane; j < dg; j += 64) {
        int s = esrc[base + j];
        float e = el[s] + erd;
        e = (e >= 0.f) ? e : 0.2f * e;
        if (j < 64) { sreg = s; ereg = e; }
        m = fmaxf(m, e);
    }
#pragma unroll
    for (int off = 32; off >= 1; off >>= 1)
        m = fmaxf(m, __shfl_xor(m, off));

    float acc = 0.f, den = 0.f;
    if (dg <= 64) {
        for (int j = 0; j < dg; ++j) {
            int   s = __shfl(sreg, j);
            float e = __shfl(ereg, j);
            float ee = __expf(e - m);
            den += ee;
            acc += ee * feat[(size_t)s * HF + lane];
        }
    } else {
        for (int j = 0; j < dg; ++j) {
            int s = esrc[base + j];
            float e = el[s] + erd;
            e = (e >= 0.f) ? e : 0.2f * e;
            float ee = __expf(e - m);
            den += ee;
            acc += ee * feat[(size_t)s * HF + lane];
        }
    }

    float o = (dg > 0) ? (acc / den) : 0.f;
    out[(size_t)node * HF + lane] = fmaxf(o + bias[lane], 0.f);
}

extern "C" void kernel_launch(void* const* d_in, const int* in_sizes, int n_in,
                              void* d_out, int out_size, void* d_ws, size_t ws_size,
                              hipStream_t stream) {
    const int N = NNODES;
    const int E = NEDGES;

    const float* in_feat = (const float*)d_in[0];
    const float* W1 = (const float*)d_in[1];
    const float* al1 = (const float*)d_in[2];
    const float* ar1 = (const float*)d_in[3];
    const float* b1 = (const float*)d_in[4];
    const float* W2 = (const float*)d_in[5];
    const float* al2 = (const float*)d_in[6];
    const float* ar2 = (const float*)d_in[7];
    const float* b2 = (const float*)d_in[8];
    const float* W3 = (const float*)d_in[9];
    const float* al3 = (const float*)d_in[10];
    const float* ar3 = (const float*)d_in[11];
    const float* b3 = (const float*)d_in[12];
    const int* src = (const int*)d_in[13];
    const int* dst = (const int*)d_in[14];

    float* ws = (float*)d_ws;
    float* feat = ws;                          // N*64
    float* h1   = feat + (size_t)N * HF;       // N*64 (aliased by ebuf2 pre-layer1)
    float* h2   = h1 + (size_t)N * HF;         // N*64
    float* el   = h2 + (size_t)N * HF;         // N
    float* er   = el + N;                      // N
    int* deg    = (int*)(er + N);              // N
    int* cur    = deg + N;                     // N
    int* bsum   = cur + N;                     // 256
    int* gcur   = bsum + 256;                  // 256
    int* esrc   = gcur + 256;                  // E
    int2* ebuf2 = (int2*)h1;                   // E int2 (12.8MB of h1's 25.6MB)

    const int NB1024 = (N + 1023) / 1024;
    const int gEdge = (E + 255) / 256;
    const int gNode4 = (N + 3) / 4;
    const int gN256 = (N + 255) / 256;
    const int gTile = (N + 127) / 128;

    // ---- CSR build (same graph for all 3 layers) ----
    hipMemsetAsync(deg, 0, (size_t)N * 4, stream);
    k_hist<<<gEdge, 256, 0, stream>>>(dst, deg, E);
    k_scan1<<<NB1024, 256, 0, stream>>>(deg, cur, bsum, N);
    k_scan2<<<1, 128, 0, stream>>>(bsum, NB1024);
    k_scan3<<<gN256, 256, 0, stream>>>(cur, bsum, N);
    k_bucketinit<<<1, 256, 0, stream>>>(cur, gcur, N, E);
    k_bucket<<<256, 256, 0, stream>>>(src, dst, gcur, ebuf2, E);
    k_scatter2<<<gEdge, 256, 0, stream>>>(ebuf2, cur, esrc, E);

    float* out = (float*)d_out;

    // ---- layer 1 (K=128) ----
    gemm_tile<128><<<gTile, 256, 0, stream>>>(in_feat, W1, al1, ar1, feat, el, er, N);
    node_agg<<<gNode4, 256, 0, stream>>>(cur, deg, esrc, el, er, feat, b1, h1, N);

    // ---- layer 2 (K=64) ----
    gemm_tile<64><<<gTile, 256, 0, stream>>>(h1, W2, al2, ar2, feat, el, er, N);
    node_agg<<<gNode4, 256, 0, stream>>>(cur, deg, esrc, el, er, feat, b2, h2, N);

    // ---- layer 3 (K=64) ----
    gemm_tile<64><<<gTile, 256, 0, stream>>>(h2, W3, al3, ar3, feat, el, er, N);
    node_agg<<<gNode4, 256, 0, stream>>>(cur, deg, esrc, el, er, feat, b3, out, N);
}

// Round 7
// 438.664 us; speedup vs baseline: 4.2455x; 1.2613x over previous
//
#include <hip/hip_runtime.h>
#include <math.h>

#define NNODES 100000
#define NEDGES 1600000
#define HF 64
#define NBUCK_SHIFT 9
#define NBUCK 256   // buckets actually used: (NNODES-1>>9)+1 = 196

// ======================= CSR build =======================================
__global__ __launch_bounds__(256) void k_hist(
    const int* __restrict__ dst, int* __restrict__ deg, int E)
{
    int i = blockIdx.x * 256 + threadIdx.x;
    if (i < E) atomicAdd(&deg[dst[i]], 1);
}

__global__ __launch_bounds__(256) void k_scan1(
    const int* __restrict__ deg, int* __restrict__ cur, int* __restrict__ bsum, int n)
{
    __shared__ int s[256];
    const int tid = threadIdx.x;
    const int gbase = blockIdx.x * 1024 + tid * 4;
    int v[4];
#pragma unroll
    for (int q = 0; q < 4; ++q) {
        int idx = gbase + q;
        v[q] = (idx < n) ? deg[idx] : 0;
    }
    int tsum = v[0] + v[1] + v[2] + v[3];
    s[tid] = tsum;
    __syncthreads();
    for (int off = 1; off < 256; off <<= 1) {
        int t = (tid >= off) ? s[tid - off] : 0;
        __syncthreads();
        s[tid] += t;
        __syncthreads();
    }
    int run = s[tid] - tsum;
#pragma unroll
    for (int q = 0; q < 4; ++q) {
        int idx = gbase + q;
        if (idx < n) cur[idx] = run;
        run += v[q];
    }
    if (tid == 255) bsum[blockIdx.x] = s[255];
}

__global__ __launch_bounds__(128) void k_scan2(int* __restrict__ bsum, int nb)
{
    __shared__ int s[128];
    const int tid = threadIdx.x;
    int own = (tid < nb) ? bsum[tid] : 0;
    s[tid] = own;
    __syncthreads();
    for (int off = 1; off < 128; off <<= 1) {
        int t = (tid >= off) ? s[tid - off] : 0;
        __syncthreads();
        s[tid] += t;
        __syncthreads();
    }
    if (tid < nb) bsum[tid] = s[tid] - own;
}

__global__ __launch_bounds__(256) void k_scan3(
    int* __restrict__ cur, const int* __restrict__ bsum, int n)
{
    int i = blockIdx.x * 256 + threadIdx.x;
    if (i < n) cur[i] += bsum[i >> 10];
}

__global__ __launch_bounds__(256) void k_bucketinit(
    const int* __restrict__ cur, int* __restrict__ gcur, int n, int E)
{
    int b = threadIdx.x;
    int idx = b << NBUCK_SHIFT;
    gcur[b] = (idx < n) ? cur[idx] : E;
}

__global__ __launch_bounds__(256) void k_bucket(
    const int* __restrict__ src, const int* __restrict__ dst,
    int* __restrict__ gcur, int2* __restrict__ ebuf2, int E)
{
    __shared__ int hist[NBUCK];
    const int tid = threadIdx.x;
    const int EPB = (E + 255) / 256;
    const int e0 = blockIdx.x * EPB;
    const int e1 = min(E, e0 + EPB);

    hist[tid] = 0;
    __syncthreads();
    for (int i = e0 + tid; i < e1; i += 256)
        atomicAdd(&hist[dst[i] >> NBUCK_SHIFT], 1);
    __syncthreads();
    int cnt = hist[tid];
    int base = (cnt > 0) ? atomicAdd(&gcur[tid], cnt) : 0;
    __syncthreads();
    hist[tid] = base;
    __syncthreads();
    for (int i = e0 + tid; i < e1; i += 256) {
        int d = dst[i];
        int r = atomicAdd(&hist[d >> NBUCK_SHIFT], 1);
        ebuf2[r] = make_int2(src[i], d);
    }
}

__global__ __launch_bounds__(256) void k_scatter2(
    const int2* __restrict__ ebuf2, int* __restrict__ cur,
    int* __restrict__ esrc, int E)
{
    int i = blockIdx.x * 256 + threadIdx.x;
    if (i >= E) return;
    int2 e = ebuf2[i];
    int p = atomicAdd(&cur[e.y], 1);
    esrc[p] = e.x;
}

// ======================= tiled GEMM: feat = x@W^T, el, er ================
template <int K>
__global__ __launch_bounds__(256) void gemm_tile(
    const float* __restrict__ x, const float* __restrict__ W,
    const float* __restrict__ al, const float* __restrict__ ar,
    float* __restrict__ feat, float* __restrict__ el, float* __restrict__ er,
    int n)
{
    constexpr int KS = 32;
    __shared__ float xs[KS][132];
    __shared__ float wt[KS][68];

    const int tid = threadIdx.x;
    const int tx = tid & 15;
    const int ty = tid >> 4;
    const int row0 = blockIdx.x * 128;

    float acc[8][4];
#pragma unroll
    for (int i = 0; i < 8; ++i)
#pragma unroll
        for (int j = 0; j < 4; ++j) acc[i][j] = 0.f;

    for (int ks = 0; ks < K; ks += KS) {
        if (ks) __syncthreads();
#pragma unroll
        for (int jj = 0; jj < 4; ++jj) {
            int j = tid + jj * 256;
            int r = j >> 3;
            int k4 = j & 7;
            int gr = row0 + r;
            float4 v = make_float4(0.f, 0.f, 0.f, 0.f);
            if (gr < n) v = *(const float4*)(x + (size_t)gr * K + ks + 4 * k4);
            xs[4 * k4 + 0][r] = v.x;
            xs[4 * k4 + 1][r] = v.y;
            xs[4 * k4 + 2][r] = v.z;
            xs[4 * k4 + 3][r] = v.w;
        }
#pragma unroll
        for (int jj = 0; jj < 2; ++jj) {
            int j = tid + jj * 256;
            int c = j >> 3;
            int k4 = j & 7;
            float4 v = *(const float4*)(W + (size_t)c * K + ks + 4 * k4);
            wt[4 * k4 + 0][c] = v.x;
            wt[4 * k4 + 1][c] = v.y;
            wt[4 * k4 + 2][c] = v.z;
            wt[4 * k4 + 3][c] = v.w;
        }
        __syncthreads();

#pragma unroll 8
        for (int k = 0; k < KS; ++k) {
            float4 a0 = *(const float4*)&xs[k][8 * ty + 0];
            float4 a1 = *(const float4*)&xs[k][8 * ty + 4];
            float4 b  = *(const float4*)&wt[k][4 * tx];
            float ar_[8] = {a0.x, a0.y, a0.z, a0.w, a1.x, a1.y, a1.z, a1.w};
            float bc[4] = {b.x, b.y, b.z, b.w};
#pragma unroll
            for (int i = 0; i < 8; ++i)
#pragma unroll
                for (int j = 0; j < 4; ++j)
                    acc[i][j] += ar_[i] * bc[j];
        }
    }

    const float4 ald = *(const float4*)(al + 4 * tx);
    const float4 ard = *(const float4*)(ar + 4 * tx);
#pragma unroll
    for (int i = 0; i < 8; ++i) {
        int row = row0 + 8 * ty + i;
        float pl = acc[i][0] * ald.x + acc[i][1] * ald.y +
                   acc[i][2] * ald.z + acc[i][3] * ald.w;
        float pr = acc[i][0] * ard.x + acc[i][1] * ard.y +
                   acc[i][2] * ard.z + acc[i][3] * ard.w;
#pragma unroll
        for (int off = 8; off >= 1; off >>= 1) {
            pl += __shfl_xor(pl, off);
            pr += __shfl_xor(pr, off);
        }
        if (row < n) {
            float4 st = make_float4(acc[i][0], acc[i][1], acc[i][2], acc[i][3]);
            *(float4*)(feat + (size_t)row * HF + 4 * tx) = st;
            if (tx == 0) { el[row] = pl; er[row] = pr; }
        }
    }
}

// ======================= fused per-node softmax-aggregate =================
// one wave per dst node. Fast path (deg<=64): lane-parallel softmax, then
// 4 edges/iteration (lane-group lg owns edge j0+lg, 16 lanes x float4 row).
__global__ __launch_bounds__(256) void node_agg(
    const int* __restrict__ cur, const int* __restrict__ deg,
    const int* __restrict__ esrc,
    const float* __restrict__ el, const float* __restrict__ er,
    const float* __restrict__ feat, const float* __restrict__ bias,
    float* __restrict__ out, int n)
{
    const int node = blockIdx.x * 4 + (threadIdx.x >> 6);
    if (node >= n) return;
    const int lane = threadIdx.x & 63;
    const int cx = lane & 15;       // column group (float4)
    const int lg = lane >> 4;       // edge slot within iteration

    const int dg = deg[node];

    if (dg == 0) {
        if (lane < 16) {
            float4 b4 = *(const float4*)(bias + 4 * cx);
            float4 o;
            o.x = fmaxf(b4.x, 0.f); o.y = fmaxf(b4.y, 0.f);
            o.z = fmaxf(b4.z, 0.f); o.w = fmaxf(b4.w, 0.f);
            *(float4*)(out + (size_t)node * HF + 4 * cx) = o;
        }
        return;
    }

    const int base = cur[node] - dg;
    const float erd = er[node];

    if (dg <= 64) {
        // phase 1: lane j owns edge j — leaky-relu, max, exp, den (parallel)
        int sreg = 0;
        float ereg = -INFINITY;
        if (lane < dg) {
            sreg = esrc[base + lane];
            float e = el[sreg] + erd;
            ereg = (e >= 0.f) ? e : 0.2f * e;
        }
        float m = ereg;
#pragma unroll
        for (int off = 32; off >= 1; off >>= 1)
            m = fmaxf(m, __shfl_xor(m, off));
        float ee = __expf(ereg - m);          // 0 for inactive lanes
        float den = ee;
#pragma unroll
        for (int off = 32; off >= 1; off >>= 1)
            den += __shfl_xor(den, off);

        // phase 2: 4 edges per iteration, float4 per lane
        float4 acc = make_float4(0.f, 0.f, 0.f, 0.f);
        for (int j0 = 0; j0 < dg; j0 += 4) {
            int jj = j0 + lg;
            int   s = __shfl(sreg, jj);
            float w = __shfl(ee, jj);
            if (jj < dg) {
                float4 f = *(const float4*)(feat + (size_t)s * HF + 4 * cx);
                acc.x += w * f.x;
                acc.y += w * f.y;
                acc.z += w * f.z;
                acc.w += w * f.w;
            }
        }
        // reduce across the 4 lane-groups
#pragma unroll
        for (int off = 16; off <= 32; off <<= 1) {
            acc.x += __shfl_xor(acc.x, off);
            acc.y += __shfl_xor(acc.y, off);
            acc.z += __shfl_xor(acc.z, off);
            acc.w += __shfl_xor(acc.w, off);
        }
        if (lane < 16) {
            float inv = 1.f / den;
            float4 b4 = *(const float4*)(bias + 4 * cx);
            float4 o;
            o.x = fmaxf(acc.x * inv + b4.x, 0.f);
            o.y = fmaxf(acc.y * inv + b4.y, 0.f);
            o.z = fmaxf(acc.z * inv + b4.z, 0.f);
            o.w = fmaxf(acc.w * inv + b4.w, 0.f);
            *(float4*)(out + (size_t)node * HF + 4 * cx) = o;
        }
        return;
    }

    // slow path (deg > 64): original serial version
    float m = -INFINITY;
    for (int j = lane; j < dg; j += 64) {
        int s = esrc[base + j];
        float e = el[s] + erd;
        e = (e >= 0.f) ? e : 0.2f * e;
        m = fmaxf(m, e);
    }
#pragma unroll
    for (int off = 32; off >= 1; off >>= 1)
        m = fmaxf(m, __shfl_xor(m, off));

    float acc = 0.f, den = 0.f;
    for (int j = 0; j < dg; ++j) {
        int s = esrc[base + j];
        float e = el[s] + erd;
        e = (e >= 0.f) ? e : 0.2f * e;
        float ee = __expf(e - m);
        den += ee;
        acc += ee * feat[(size_t)s * HF + lane];
    }
    out[(size_t)node * HF + lane] = fmaxf(acc / den + bias[lane], 0.f);
}

extern "C" void kernel_launch(void* const* d_in, const int* in_sizes, int n_in,
                              void* d_out, int out_size, void* d_ws, size_t ws_size,
                              hipStream_t stream) {
    const int N = NNODES;
    const int E = NEDGES;

    const float* in_feat = (const float*)d_in[0];
    const float* W1 = (const float*)d_in[1];
    const float* al1 = (const float*)d_in[2];
    const float* ar1 = (const float*)d_in[3];
    const float* b1 = (const float*)d_in[4];
    const float* W2 = (const float*)d_in[5];
    const float* al2 = (const float*)d_in[6];
    const float* ar2 = (const float*)d_in[7];
    const float* b2 = (const float*)d_in[8];
    const float* W3 = (const float*)d_in[9];
    const float* al3 = (const float*)d_in[10];
    const float* ar3 = (const float*)d_in[11];
    const float* b3 = (const float*)d_in[12];
    const int* src = (const int*)d_in[13];
    const int* dst = (const int*)d_in[14];

    float* ws = (float*)d_ws;
    float* feat = ws;                          // N*64
    float* h1   = feat + (size_t)N * HF;       // N*64 (aliased by ebuf2 pre-layer1)
    float* h2   = h1 + (size_t)N * HF;         // N*64
    float* el   = h2 + (size_t)N * HF;         // N
    float* er   = el + N;                      // N
    int* deg    = (int*)(er + N);              // N
    int* cur    = deg + N;                     // N
    int* bsum   = cur + N;                     // 256
    int* gcur   = bsum + 256;                  // 256
    int* esrc   = gcur + 256;                  // E
    int2* ebuf2 = (int2*)h1;                   // E int2 (12.8MB of h1's 25.6MB)

    const int NB1024 = (N + 1023) / 1024;
    const int gEdge = (E + 255) / 256;
    const int gNode4 = (N + 3) / 4;
    const int gN256 = (N + 255) / 256;
    const int gTile = (N + 127) / 128;

    // ---- CSR build (same graph for all 3 layers) ----
    hipMemsetAsync(deg, 0, (size_t)N * 4, stream);
    k_hist<<<gEdge, 256, 0, stream>>>(dst, deg, E);
    k_scan1<<<NB1024, 256, 0, stream>>>(deg, cur, bsum, N);
    k_scan2<<<1, 128, 0, stream>>>(bsum, NB1024);
    k_scan3<<<gN256, 256, 0, stream>>>(cur, bsum, N);
    k_bucketinit<<<1, 256, 0, stream>>>(cur, gcur, N, E);
    k_bucket<<<256, 256, 0, stream>>>(src, dst, gcur, ebuf2, E);
    k_scatter2<<<gEdge, 256, 0, stream>>>(ebuf2, cur, esrc, E);

    float* out = (float*)d_out;

    // ---- layer 1 (K=128) ----
    gemm_tile<128><<<gTile, 256, 0, stream>>>(in_feat, W1, al1, ar1, feat, el, er, N);
    node_agg<<<gNode4, 256, 0, stream>>>(cur, deg, esrc, el, er, feat, b1, h1, N);

    // ---- layer 2 (K=64) ----
    gemm_tile<64><<<gTile, 256, 0, stream>>>(h1, W2, al2, ar2, feat, el, er, N);
    node_agg<<<gNode4, 256, 0, stream>>>(cur, deg, esrc, el, er, feat, b2, h2, N);

    // ---- layer 3 (K=64) ----
    gemm_tile<64><<<gTile, 256, 0, stream>>>(h2, W3, al3, ar3, feat, el, er, N);
    node_agg<<<gNode4, 256, 0, stream>>>(cur, deg, esrc, el, er, feat, b3, out, N);
}

// Round 8
// 431.927 us; speedup vs baseline: 4.3117x; 1.0156x over previous
//
#include <hip/hip_runtime.h>
#include <math.h>

#define NNODES 100000
#define NEDGES 1600000
#define HF 64
#define NBUCK_SHIFT 9
#define NBUCK 256   // buckets actually used: (NNODES-1>>9)+1 = 196

// ======================= CSR build =======================================
__global__ __launch_bounds__(256) void k_hist(
    const int* __restrict__ dst, int* __restrict__ deg, int E)
{
    int i = blockIdx.x * 256 + threadIdx.x;
    if (i < E) atomicAdd(&deg[dst[i]], 1);
}

__global__ __launch_bounds__(256) void k_scan1(
    const int* __restrict__ deg, int* __restrict__ cur, int* __restrict__ bsum, int n)
{
    __shared__ int s[256];
    const int tid = threadIdx.x;
    const int gbase = blockIdx.x * 1024 + tid * 4;
    int v[4];
#pragma unroll
    for (int q = 0; q < 4; ++q) {
        int idx = gbase + q;
        v[q] = (idx < n) ? deg[idx] : 0;
    }
    int tsum = v[0] + v[1] + v[2] + v[3];
    s[tid] = tsum;
    __syncthreads();
    for (int off = 1; off < 256; off <<= 1) {
        int t = (tid >= off) ? s[tid - off] : 0;
        __syncthreads();
        s[tid] += t;
        __syncthreads();
    }
    int run = s[tid] - tsum;
#pragma unroll
    for (int q = 0; q < 4; ++q) {
        int idx = gbase + q;
        if (idx < n) cur[idx] = run;
        run += v[q];
    }
    if (tid == 255) bsum[blockIdx.x] = s[255];
}

__global__ __launch_bounds__(128) void k_scan2(int* __restrict__ bsum, int nb)
{
    __shared__ int s[128];
    const int tid = threadIdx.x;
    int own = (tid < nb) ? bsum[tid] : 0;
    s[tid] = own;
    __syncthreads();
    for (int off = 1; off < 128; off <<= 1) {
        int t = (tid >= off) ? s[tid - off] : 0;
        __syncthreads();
        s[tid] += t;
        __syncthreads();
    }
    if (tid < nb) bsum[tid] = s[tid] - own;
}

__global__ __launch_bounds__(256) void k_scan3(
    int* __restrict__ cur, const int* __restrict__ bsum, int n)
{
    int i = blockIdx.x * 256 + threadIdx.x;
    if (i < n) cur[i] += bsum[i >> 10];
}

__global__ __launch_bounds__(256) void k_bucketinit(
    const int* __restrict__ cur, int* __restrict__ gcur, int n, int E)
{
    int b = threadIdx.x;
    int idx = b << NBUCK_SHIFT;
    gcur[b] = (idx < n) ? cur[idx] : E;
}

__global__ __launch_bounds__(256) void k_bucket(
    const int* __restrict__ src, const int* __restrict__ dst,
    int* __restrict__ gcur, int2* __restrict__ ebuf2, int E)
{
    __shared__ int hist[NBUCK];
    const int tid = threadIdx.x;
    const int EPB = (E + 255) / 256;
    const int e0 = blockIdx.x * EPB;
    const int e1 = min(E, e0 + EPB);

    hist[tid] = 0;
    __syncthreads();
    for (int i = e0 + tid; i < e1; i += 256)
        atomicAdd(&hist[dst[i] >> NBUCK_SHIFT], 1);
    __syncthreads();
    int cnt = hist[tid];
    int base = (cnt > 0) ? atomicAdd(&gcur[tid], cnt) : 0;
    __syncthreads();
    hist[tid] = base;
    __syncthreads();
    for (int i = e0 + tid; i < e1; i += 256) {
        int d = dst[i];
        int r = atomicAdd(&hist[d >> NBUCK_SHIFT], 1);
        ebuf2[r] = make_int2(src[i], d);
    }
}

__global__ __launch_bounds__(256) void k_scatter2(
    const int2* __restrict__ ebuf2, int* __restrict__ cur,
    int* __restrict__ esrc, int E)
{
    int i = blockIdx.x * 256 + threadIdx.x;
    if (i >= E) return;
    int2 e = ebuf2[i];
    int p = atomicAdd(&cur[e.y], 1);
    esrc[p] = e.x;
}

// ======================= tiled GEMM: feat = x@W^T, el, er ================
template <int K>
__global__ __launch_bounds__(256) void gemm_tile(
    const float* __restrict__ x, const float* __restrict__ W,
    const float* __restrict__ al, const float* __restrict__ ar,
    float* __restrict__ feat, float* __restrict__ el, float* __restrict__ er,
    int n)
{
    constexpr int KS = 32;
    __shared__ float xs[KS][132];
    __shared__ float wt[KS][68];

    const int tid = threadIdx.x;
    const int tx = tid & 15;
    const int ty = tid >> 4;
    const int row0 = blockIdx.x * 128;

    float acc[8][4];
#pragma unroll
    for (int i = 0; i < 8; ++i)
#pragma unroll
        for (int j = 0; j < 4; ++j) acc[i][j] = 0.f;

    for (int ks = 0; ks < K; ks += KS) {
        if (ks) __syncthreads();
#pragma unroll
        for (int jj = 0; jj < 4; ++jj) {
            int j = tid + jj * 256;
            int r = j >> 3;
            int k4 = j & 7;
            int gr = row0 + r;
            float4 v = make_float4(0.f, 0.f, 0.f, 0.f);
            if (gr < n) v = *(const float4*)(x + (size_t)gr * K + ks + 4 * k4);
            xs[4 * k4 + 0][r] = v.x;
            xs[4 * k4 + 1][r] = v.y;
            xs[4 * k4 + 2][r] = v.z;
            xs[4 * k4 + 3][r] = v.w;
        }
#pragma unroll
        for (int jj = 0; jj < 2; ++jj) {
            int j = tid + jj * 256;
            int c = j >> 3;
            int k4 = j & 7;
            float4 v = *(const float4*)(W + (size_t)c * K + ks + 4 * k4);
            wt[4 * k4 + 0][c] = v.x;
            wt[4 * k4 + 1][c] = v.y;
            wt[4 * k4 + 2][c] = v.z;
            wt[4 * k4 + 3][c] = v.w;
        }
        __syncthreads();

#pragma unroll 8
        for (int k = 0; k < KS; ++k) {
            float4 a0 = *(const float4*)&xs[k][8 * ty + 0];
            float4 a1 = *(const float4*)&xs[k][8 * ty + 4];
            float4 b  = *(const float4*)&wt[k][4 * tx];
            float ar_[8] = {a0.x, a0.y, a0.z, a0.w, a1.x, a1.y, a1.z, a1.w};
            float bc[4] = {b.x, b.y, b.z, b.w};
#pragma unroll
            for (int i = 0; i < 8; ++i)
#pragma unroll
                for (int j = 0; j < 4; ++j)
                    acc[i][j] += ar_[i] * bc[j];
        }
    }

    const float4 ald = *(const float4*)(al + 4 * tx);
    const float4 ard = *(const float4*)(ar + 4 * tx);
#pragma unroll
    for (int i = 0; i < 8; ++i) {
        int row = row0 + 8 * ty + i;
        float pl = acc[i][0] * ald.x + acc[i][1] * ald.y +
                   acc[i][2] * ald.z + acc[i][3] * ald.w;
        float pr = acc[i][0] * ard.x + acc[i][1] * ard.y +
                   acc[i][2] * ard.z + acc[i][3] * ard.w;
#pragma unroll
        for (int off = 8; off >= 1; off >>= 1) {
            pl += __shfl_xor(pl, off);
            pr += __shfl_xor(pr, off);
        }
        if (row < n) {
            float4 st = make_float4(acc[i][0], acc[i][1], acc[i][2], acc[i][3]);
            *(float4*)(feat + (size_t)row * HF + 4 * tx) = st;
            if (tx == 0) { el[row] = pl; er[row] = pr; }
        }
    }
}

// ======================= fused per-node softmax-aggregate =================
// one wave per dst node. Fast path (deg<=64): lane-parallel softmax into an
// LDS edge table (src, ee), then 16 edges/iteration with 4 independent
// accumulator chains (4 outstanding float4 gathers per lane).
__global__ __launch_bounds__(256) void node_agg(
    const int* __restrict__ cur, const int* __restrict__ deg,
    const int* __restrict__ esrc,
    const float* __restrict__ el, const float* __restrict__ er,
    const float* __restrict__ feat, const float* __restrict__ bias,
    float* __restrict__ out, int n)
{
    __shared__ float2 sed[4][64];   // per-wave (src, ee) edge table

    const int wv = threadIdx.x >> 6;
    const int node = blockIdx.x * 4 + wv;
    if (node >= n) return;
    const int lane = threadIdx.x & 63;
    const int cx = lane & 15;       // column group (float4)
    const int lg = lane >> 4;       // edge slot within iteration

    const int dg = deg[node];

    if (dg == 0) {
        if (lane < 16) {
            float4 b4 = *(const float4*)(bias + 4 * cx);
            float4 o;
            o.x = fmaxf(b4.x, 0.f); o.y = fmaxf(b4.y, 0.f);
            o.z = fmaxf(b4.z, 0.f); o.w = fmaxf(b4.w, 0.f);
            *(float4*)(out + (size_t)node * HF + 4 * cx) = o;
        }
        return;
    }

    const int base = cur[node] - dg;
    const float erd = er[node];

    if (dg <= 64) {
        // phase 1: lane j owns edge j — leaky-relu, max, exp, den (parallel)
        int sreg = 0;
        float ereg = -INFINITY;
        if (lane < dg) {
            sreg = esrc[base + lane];
            float e = el[sreg] + erd;
            ereg = (e >= 0.f) ? e : 0.2f * e;
        }
        float m = ereg;
#pragma unroll
        for (int off = 32; off >= 1; off >>= 1)
            m = fmaxf(m, __shfl_xor(m, off));
        float ee = __expf(ereg - m);          // ~0 for inactive lanes
        float den = ee;
#pragma unroll
        for (int off = 32; off >= 1; off >>= 1)
            den += __shfl_xor(den, off);
        if (lane < dg)
            sed[wv][lane] = make_float2(__int_as_float(sreg), ee);
        // same-wave LDS RAW: compiler inserts lgkmcnt wait; no barrier needed

        // phase 2: 16 edges/iter, 4 independent chains, 4 loads in flight
        float4 a0 = make_float4(0.f, 0.f, 0.f, 0.f);
        float4 a1 = a0, a2 = a0, a3 = a0;
        for (int j0 = 0; j0 < dg; j0 += 16) {
            const int ja = j0 + lg;
            const int jb = ja + 4;
            const int jc = ja + 8;
            const int jd = ja + 12;
            float2 pa = sed[wv][ja & 63];
            float2 pb = sed[wv][jb & 63];
            float2 pc = sed[wv][jc & 63];
            float2 pd = sed[wv][jd & 63];
            float4 fa, fb, fc, fd;
            if (ja < dg) fa = *(const float4*)(feat + (size_t)__float_as_int(pa.x) * HF + 4 * cx);
            if (jb < dg) fb = *(const float4*)(feat + (size_t)__float_as_int(pb.x) * HF + 4 * cx);
            if (jc < dg) fc = *(const float4*)(feat + (size_t)__float_as_int(pc.x) * HF + 4 * cx);
            if (jd < dg) fd = *(const float4*)(feat + (size_t)__float_as_int(pd.x) * HF + 4 * cx);
            if (ja < dg) { a0.x += pa.y * fa.x; a0.y += pa.y * fa.y; a0.z += pa.y * fa.z; a0.w += pa.y * fa.w; }
            if (jb < dg) { a1.x += pb.y * fb.x; a1.y += pb.y * fb.y; a1.z += pb.y * fb.z; a1.w += pb.y * fb.w; }
            if (jc < dg) { a2.x += pc.y * fc.x; a2.y += pc.y * fc.y; a2.z += pc.y * fc.z; a2.w += pc.y * fc.w; }
            if (jd < dg) { a3.x += pd.y * fd.x; a3.y += pd.y * fd.y; a3.z += pd.y * fd.z; a3.w += pd.y * fd.w; }
        }
        float4 acc;
        acc.x = (a0.x + a1.x) + (a2.x + a3.x);
        acc.y = (a0.y + a1.y) + (a2.y + a3.y);
        acc.z = (a0.z + a1.z) + (a2.z + a3.z);
        acc.w = (a0.w + a1.w) + (a2.w + a3.w);
        // reduce across the 4 lane-groups
#pragma unroll
        for (int off = 16; off <= 32; off <<= 1) {
            acc.x += __shfl_xor(acc.x, off);
            acc.y += __shfl_xor(acc.y, off);
            acc.z += __shfl_xor(acc.z, off);
            acc.w += __shfl_xor(acc.w, off);
        }
        if (lane < 16) {
            float inv = 1.f / den;
            float4 b4 = *(const float4*)(bias + 4 * cx);
            float4 o;
            o.x = fmaxf(acc.x * inv + b4.x, 0.f);
            o.y = fmaxf(acc.y * inv + b4.y, 0.f);
            o.z = fmaxf(acc.z * inv + b4.z, 0.f);
            o.w = fmaxf(acc.w * inv + b4.w, 0.f);
            *(float4*)(out + (size_t)node * HF + 4 * cx) = o;
        }
        return;
    }

    // slow path (deg > 64): serial reference version
    float m = -INFINITY;
    for (int j = lane; j < dg; j += 64) {
        int s = esrc[base + j];
        float e = el[s] + erd;
        e = (e >= 0.f) ? e : 0.2f * e;
        m = fmaxf(m, e);
    }
#pragma unroll
    for (int off = 32; off >= 1; off >>= 1)
        m = fmaxf(m, __shfl_xor(m, off));

    float acc = 0.f, den = 0.f;
    for (int j = 0; j < dg; ++j) {
        int s = esrc[base + j];
        float e = el[s] + erd;
        e = (e >= 0.f) ? e : 0.2f * e;
        float ee = __expf(e - m);
        den += ee;
        acc += ee * feat[(size_t)s * HF + lane];
    }
    out[(size_t)node * HF + lane] = fmaxf(acc / den + bias[lane], 0.f);
}

extern "C" void kernel_launch(void* const* d_in, const int* in_sizes, int n_in,
                              void* d_out, int out_size, void* d_ws, size_t ws_size,
                              hipStream_t stream) {
    const int N = NNODES;
    const int E = NEDGES;

    const float* in_feat = (const float*)d_in[0];
    const float* W1 = (const float*)d_in[1];
    const float* al1 = (const float*)d_in[2];
    const float* ar1 = (const float*)d_in[3];
    const float* b1 = (const float*)d_in[4];
    const float* W2 = (const float*)d_in[5];
    const float* al2 = (const float*)d_in[6];
    const float* ar2 = (const float*)d_in[7];
    const float* b2 = (const float*)d_in[8];
    const float* W3 = (const float*)d_in[9];
    const float* al3 = (const float*)d_in[10];
    const float* ar3 = (const float*)d_in[11];
    const float* b3 = (const float*)d_in[12];
    const int* src = (const int*)d_in[13];
    const int* dst = (const int*)d_in[14];

    float* ws = (float*)d_ws;
    float* feat = ws;                          // N*64
    float* h1   = feat + (size_t)N * HF;       // N*64 (aliased by ebuf2 pre-layer1)
    float* h2   = h1 + (size_t)N * HF;         // N*64
    float* el   = h2 + (size_t)N * HF;         // N
    float* er   = el + N;                      // N
    int* deg    = (int*)(er + N);              // N
    int* cur    = deg + N;                     // N
    int* bsum   = cur + N;                     // 256
    int* gcur   = bsum + 256;                  // 256
    int* esrc   = gcur + 256;                  // E
    int2* ebuf2 = (int2*)h1;                   // E int2 (12.8MB of h1's 25.6MB)

    const int NB1024 = (N + 1023) / 1024;
    const int gEdge = (E + 255) / 256;
    const int gNode4 = (N + 3) / 4;
    const int gN256 = (N + 255) / 256;
    const int gTile = (N + 127) / 128;

    // ---- CSR build (same graph for all 3 layers) ----
    hipMemsetAsync(deg, 0, (size_t)N * 4, stream);
    k_hist<<<gEdge, 256, 0, stream>>>(dst, deg, E);
    k_scan1<<<NB1024, 256, 0, stream>>>(deg, cur, bsum, N);
    k_scan2<<<1, 128, 0, stream>>>(bsum, NB1024);
    k_scan3<<<gN256, 256, 0, stream>>>(cur, bsum, N);
    k_bucketinit<<<1, 256, 0, stream>>>(cur, gcur, N, E);
    k_bucket<<<256, 256, 0, stream>>>(src, dst, gcur, ebuf2, E);
    k_scatter2<<<gEdge, 256, 0, stream>>>(ebuf2, cur, esrc, E);

    float* out = (float*)d_out;

    // ---- layer 1 (K=128) ----
    gemm_tile<128><<<gTile, 256, 0, stream>>>(in_feat, W1, al1, ar1, feat, el, er, N);
    node_agg<<<gNode4, 256, 0, stream>>>(cur, deg, esrc, el, er, feat, b1, h1, N);

    // ---- layer 2 (K=64) ----
    gemm_tile<64><<<gTile, 256, 0, stream>>>(h1, W2, al2, ar2, feat, el, er, N);
    node_agg<<<gNode4, 256, 0, stream>>>(cur, deg, esrc, el, er, feat, b2, h2, N);

    // ---- layer 3 (K=64) ----
    gemm_tile<64><<<gTile, 256, 0, stream>>>(h2, W3, al3, ar3, feat, el, er, N);
    node_agg<<<gNode4, 256, 0, stream>>>(cur, deg, esrc, el, er, feat, b3, out, N);
}

// Round 9
// 411.345 us; speedup vs baseline: 4.5275x; 1.0500x over previous
//
#include <hip/hip_runtime.h>
#include <math.h>

#define NNODES 100000
#define NEDGES 1600000
#define HF 64
#define NBUCK_SHIFT 9
#define NBUCK 256   // buckets actually used: (NNODES-1>>9)+1 = 196

// ======================= CSR build =======================================
__global__ __launch_bounds__(256) void k_hist(
    const int* __restrict__ dst, int* __restrict__ deg, int E)
{
    int i = blockIdx.x * 256 + threadIdx.x;
    if (i < E) atomicAdd(&deg[dst[i]], 1);
}

__global__ __launch_bounds__(256) void k_scan1(
    const int* __restrict__ deg, int* __restrict__ cur, int* __restrict__ bsum, int n)
{
    __shared__ int s[256];
    const int tid = threadIdx.x;
    const int gbase = blockIdx.x * 1024 + tid * 4;
    int v[4];
#pragma unroll
    for (int q = 0; q < 4; ++q) {
        int idx = gbase + q;
        v[q] = (idx < n) ? deg[idx] : 0;
    }
    int tsum = v[0] + v[1] + v[2] + v[3];
    s[tid] = tsum;
    __syncthreads();
    for (int off = 1; off < 256; off <<= 1) {
        int t = (tid >= off) ? s[tid - off] : 0;
        __syncthreads();
        s[tid] += t;
        __syncthreads();
    }
    int run = s[tid] - tsum;
#pragma unroll
    for (int q = 0; q < 4; ++q) {
        int idx = gbase + q;
        if (idx < n) cur[idx] = run;
        run += v[q];
    }
    if (tid == 255) bsum[blockIdx.x] = s[255];
}

__global__ __launch_bounds__(128) void k_scan2(int* __restrict__ bsum, int nb)
{
    __shared__ int s[128];
    const int tid = threadIdx.x;
    int own = (tid < nb) ? bsum[tid] : 0;
    s[tid] = own;
    __syncthreads();
    for (int off = 1; off < 128; off <<= 1) {
        int t = (tid >= off) ? s[tid - off] : 0;
        __syncthreads();
        s[tid] += t;
        __syncthreads();
    }
    if (tid < nb) bsum[tid] = s[tid] - own;
}

__global__ __launch_bounds__(256) void k_scan3(
    int* __restrict__ cur, const int* __restrict__ bsum, int n)
{
    int i = blockIdx.x * 256 + threadIdx.x;
    if (i < n) cur[i] += bsum[i >> 10];
}

__global__ __launch_bounds__(256) void k_bucketinit(
    const int* __restrict__ cur, int* __restrict__ gcur, int n, int E)
{
    int b = threadIdx.x;
    int idx = b << NBUCK_SHIFT;
    gcur[b] = (idx < n) ? cur[idx] : E;
}

#define KB_BLOCKS 1024
__global__ __launch_bounds__(256) void k_bucket(
    const int* __restrict__ src, const int* __restrict__ dst,
    int* __restrict__ gcur, int2* __restrict__ ebuf2, int E)
{
    __shared__ int hist[NBUCK];
    const int tid = threadIdx.x;
    const int EPB = (E + KB_BLOCKS - 1) / KB_BLOCKS;
    const int e0 = blockIdx.x * EPB;
    const int e1 = min(E, e0 + EPB);

    hist[tid] = 0;
    __syncthreads();
    for (int i = e0 + tid; i < e1; i += 256)
        atomicAdd(&hist[dst[i] >> NBUCK_SHIFT], 1);
    __syncthreads();
    int cnt = hist[tid];
    int base = (cnt > 0) ? atomicAdd(&gcur[tid], cnt) : 0;
    __syncthreads();
    hist[tid] = base;
    __syncthreads();
    for (int i = e0 + tid; i < e1; i += 256) {
        int d = dst[i];
        int r = atomicAdd(&hist[d >> NBUCK_SHIFT], 1);
        ebuf2[r] = make_int2(src[i], d);
    }
}

__global__ __launch_bounds__(256) void k_scatter2(
    const int2* __restrict__ ebuf2, int* __restrict__ cur,
    int* __restrict__ esrc, int E)
{
    int i = blockIdx.x * 256 + threadIdx.x;
    if (i >= E) return;
    int2 e = ebuf2[i];
    int p = atomicAdd(&cur[e.y], 1);
    esrc[p] = e.x;
}

// ======================= tiled GEMM: feat = x@W^T, el, er ================
template <int K>
__global__ __launch_bounds__(256) void gemm_tile(
    const float* __restrict__ x, const float* __restrict__ W,
    const float* __restrict__ al, const float* __restrict__ ar,
    float* __restrict__ feat, float* __restrict__ el, float* __restrict__ er,
    int n)
{
    constexpr int KS = 32;
    __shared__ float xs[KS][132];
    __shared__ float wt[KS][68];

    const int tid = threadIdx.x;
    const int tx = tid & 15;
    const int ty = tid >> 4;
    const int row0 = blockIdx.x * 128;

    float acc[8][4];
#pragma unroll
    for (int i = 0; i < 8; ++i)
#pragma unroll
        for (int j = 0; j < 4; ++j) acc[i][j] = 0.f;

    for (int ks = 0; ks < K; ks += KS) {
        if (ks) __syncthreads();
#pragma unroll
        for (int jj = 0; jj < 4; ++jj) {
            int j = tid + jj * 256;
            int r = j >> 3;
            int k4 = j & 7;
            int gr = row0 + r;
            float4 v = make_float4(0.f, 0.f, 0.f, 0.f);
            if (gr < n) v = *(const float4*)(x + (size_t)gr * K + ks + 4 * k4);
            xs[4 * k4 + 0][r] = v.x;
            xs[4 * k4 + 1][r] = v.y;
            xs[4 * k4 + 2][r] = v.z;
            xs[4 * k4 + 3][r] = v.w;
        }
#pragma unroll
        for (int jj = 0; jj < 2; ++jj) {
            int j = tid + jj * 256;
            int c = j >> 3;
            int k4 = j & 7;
            float4 v = *(const float4*)(W + (size_t)c * K + ks + 4 * k4);
            wt[4 * k4 + 0][c] = v.x;
            wt[4 * k4 + 1][c] = v.y;
            wt[4 * k4 + 2][c] = v.z;
            wt[4 * k4 + 3][c] = v.w;
        }
        __syncthreads();

#pragma unroll 8
        for (int k = 0; k < KS; ++k) {
            float4 a0 = *(const float4*)&xs[k][8 * ty + 0];
            float4 a1 = *(const float4*)&xs[k][8 * ty + 4];
            float4 b  = *(const float4*)&wt[k][4 * tx];
            float ar_[8] = {a0.x, a0.y, a0.z, a0.w, a1.x, a1.y, a1.z, a1.w};
            float bc[4] = {b.x, b.y, b.z, b.w};
#pragma unroll
            for (int i = 0; i < 8; ++i)
#pragma unroll
                for (int j = 0; j < 4; ++j)
                    acc[i][j] += ar_[i] * bc[j];
        }
    }

    const float4 ald = *(const float4*)(al + 4 * tx);
    const float4 ard = *(const float4*)(ar + 4 * tx);
#pragma unroll
    for (int i = 0; i < 8; ++i) {
        int row = row0 + 8 * ty + i;
        float pl = acc[i][0] * ald.x + acc[i][1] * ald.y +
                   acc[i][2] * ald.z + acc[i][3] * ald.w;
        float pr = acc[i][0] * ard.x + acc[i][1] * ard.y +
                   acc[i][2] * ard.z + acc[i][3] * ard.w;
#pragma unroll
        for (int off = 8; off >= 1; off >>= 1) {
            pl += __shfl_xor(pl, off);
            pr += __shfl_xor(pr, off);
        }
        if (row < n) {
            float4 st = make_float4(acc[i][0], acc[i][1], acc[i][2], acc[i][3]);
            *(float4*)(feat + (size_t)row * HF + 4 * tx) = st;
            if (tx == 0) { el[row] = pl; er[row] = pr; }
        }
    }
}

// ======================= fused per-node softmax-aggregate =================
// one wave per dst node. Fast path (deg<=32): issue ALL feat gathers
// immediately after esrc arrives (addresses via __shfl of sreg), run the
// softmax chain while the 8 guarded float4 loads are in flight, then FMA.
__global__ __launch_bounds__(256) void node_agg(
    const int* __restrict__ cur, const int* __restrict__ deg,
    const int* __restrict__ esrc,
    const float* __restrict__ el, const float* __restrict__ er,
    const float* __restrict__ feat, const float* __restrict__ bias,
    float* __restrict__ out, int n)
{
    const int node = blockIdx.x * 4 + (threadIdx.x >> 6);
    if (node >= n) return;
    const int lane = threadIdx.x & 63;
    const int cx = lane & 15;       // column group (float4)
    const int lg = lane >> 4;       // edge slot within round

    const int dg = deg[node];

    if (dg == 0) {
        if (lane < 16) {
            float4 b4 = *(const float4*)(bias + 4 * cx);
            float4 o;
            o.x = fmaxf(b4.x, 0.f); o.y = fmaxf(b4.y, 0.f);
            o.z = fmaxf(b4.z, 0.f); o.w = fmaxf(b4.w, 0.f);
            *(float4*)(out + (size_t)node * HF + 4 * cx) = o;
        }
        return;
    }

    const int base = cur[node] - dg;
    const float erd = er[node];

    if (dg <= 32) {
        // per-lane edge data (lane j owns edge j)
        int sreg = 0;
        if (lane < dg) sreg = esrc[base + lane];
        float elv = 0.f;
        if (lane < dg) elv = el[sreg];        // issued early

        // chain slot srcs: edge index = lg + 4*t, t=0..7 covers 0..31
        int sj[8];
#pragma unroll
        for (int t = 0; t < 8; ++t) sj[t] = __shfl(sreg, lg + 4 * t);

        // issue all guarded gathers back-to-back (8 outstanding per lane)
        float4 f[8];
#pragma unroll
        for (int t = 0; t < 8; ++t)
            if (lg + 4 * t < dg)
                f[t] = *(const float4*)(feat + (size_t)sj[t] * HF + 4 * cx);

        // softmax chain runs while gathers are in flight
        float ereg = -INFINITY;
        if (lane < dg) {
            float e = elv + erd;
            ereg = (e >= 0.f) ? e : 0.2f * e;
        }
        float m = ereg;
#pragma unroll
        for (int off = 32; off >= 1; off >>= 1)
            m = fmaxf(m, __shfl_xor(m, off));
        float ee = __expf(ereg - m);          // 0 for inactive lanes
        float den = ee;
#pragma unroll
        for (int off = 32; off >= 1; off >>= 1)
            den += __shfl_xor(den, off);

        // weighted accumulate, 4 independent chains
        float4 c[4];
#pragma unroll
        for (int q = 0; q < 4; ++q) c[q] = make_float4(0.f, 0.f, 0.f, 0.f);
#pragma unroll
        for (int t = 0; t < 8; ++t) {
            float w = __shfl(ee, lg + 4 * t);
            if (lg + 4 * t < dg) {
                c[t & 3].x += w * f[t].x;
                c[t & 3].y += w * f[t].y;
                c[t & 3].z += w * f[t].z;
                c[t & 3].w += w * f[t].w;
            }
        }
        float4 acc;
        acc.x = (c[0].x + c[1].x) + (c[2].x + c[3].x);
        acc.y = (c[0].y + c[1].y) + (c[2].y + c[3].y);
        acc.z = (c[0].z + c[1].z) + (c[2].z + c[3].z);
        acc.w = (c[0].w + c[1].w) + (c[2].w + c[3].w);
#pragma unroll
        for (int off = 16; off <= 32; off <<= 1) {
            acc.x += __shfl_xor(acc.x, off);
            acc.y += __shfl_xor(acc.y, off);
            acc.z += __shfl_xor(acc.z, off);
            acc.w += __shfl_xor(acc.w, off);
        }
        if (lane < 16) {
            float inv = 1.f / den;
            float4 b4 = *(const float4*)(bias + 4 * cx);
            float4 o;
            o.x = fmaxf(acc.x * inv + b4.x, 0.f);
            o.y = fmaxf(acc.y * inv + b4.y, 0.f);
            o.z = fmaxf(acc.z * inv + b4.z, 0.f);
            o.w = fmaxf(acc.w * inv + b4.w, 0.f);
            *(float4*)(out + (size_t)node * HF + 4 * cx) = o;
        }
        return;
    }

    if (dg <= 64) {
        // mid path: lane-parallel softmax, then 16 edges/round via shuffles
        int sreg = 0;
        float ereg = -INFINITY;
        if (lane < dg) {
            sreg = esrc[base + lane];
            float e = el[sreg] + erd;
            ereg = (e >= 0.f) ? e : 0.2f * e;
        }
        float m = ereg;
#pragma unroll
        for (int off = 32; off >= 1; off >>= 1)
            m = fmaxf(m, __shfl_xor(m, off));
        float ee = __expf(ereg - m);
        float den = ee;
#pragma unroll
        for (int off = 32; off >= 1; off >>= 1)
            den += __shfl_xor(den, off);

        float4 c[4];
#pragma unroll
        for (int q = 0; q < 4; ++q) c[q] = make_float4(0.f, 0.f, 0.f, 0.f);
        for (int j0 = 0; j0 < dg; j0 += 16) {
#pragma unroll
            for (int q = 0; q < 4; ++q) {
                int jj = j0 + lg + 4 * q;
                int   s = __shfl(sreg, jj & 63);
                float w = __shfl(ee, jj & 63);
                if (jj < dg) {
                    float4 fv = *(const float4*)(feat + (size_t)s * HF + 4 * cx);
                    c[q].x += w * fv.x;
                    c[q].y += w * fv.y;
                    c[q].z += w * fv.z;
                    c[q].w += w * fv.w;
                }
            }
        }
        float4 acc;
        acc.x = (c[0].x + c[1].x) + (c[2].x + c[3].x);
        acc.y = (c[0].y + c[1].y) + (c[2].y + c[3].y);
        acc.z = (c[0].z + c[1].z) + (c[2].z + c[3].z);
        acc.w = (c[0].w + c[1].w) + (c[2].w + c[3].w);
#pragma unroll
        for (int off = 16; off <= 32; off <<= 1) {
            acc.x += __shfl_xor(acc.x, off);
            acc.y += __shfl_xor(acc.y, off);
            acc.z += __shfl_xor(acc.z, off);
            acc.w += __shfl_xor(acc.w, off);
        }
        if (lane < 16) {
            float inv = 1.f / den;
            float4 b4 = *(const float4*)(bias + 4 * cx);
            float4 o;
            o.x = fmaxf(acc.x * inv + b4.x, 0.f);
            o.y = fmaxf(acc.y * inv + b4.y, 0.f);
            o.z = fmaxf(acc.z * inv + b4.z, 0.f);
            o.w = fmaxf(acc.w * inv + b4.w, 0.f);
            *(float4*)(out + (size_t)node * HF + 4 * cx) = o;
        }
        return;
    }

    // slow path (deg > 64): serial reference version
    float m = -INFINITY;
    for (int j = lane; j < dg; j += 64) {
        int s = esrc[base + j];
        float e = el[s] + erd;
        e = (e >= 0.f) ? e : 0.2f * e;
        m = fmaxf(m, e);
    }
#pragma unroll
    for (int off = 32; off >= 1; off >>= 1)
        m = fmaxf(m, __shfl_xor(m, off));

    float acc = 0.f, den = 0.f;
    for (int j = 0; j < dg; ++j) {
        int s = esrc[base + j];
        float e = el[s] + erd;
        e = (e >= 0.f) ? e : 0.2f * e;
        float ee = __expf(e - m);
        den += ee;
        acc += ee * feat[(size_t)s * HF + lane];
    }
    out[(size_t)node * HF + lane] = fmaxf(acc / den + bias[lane], 0.f);
}

extern "C" void kernel_launch(void* const* d_in, const int* in_sizes, int n_in,
                              void* d_out, int out_size, void* d_ws, size_t ws_size,
                              hipStream_t stream) {
    const int N = NNODES;
    const int E = NEDGES;

    const float* in_feat = (const float*)d_in[0];
    const float* W1 = (const float*)d_in[1];
    const float* al1 = (const float*)d_in[2];
    const float* ar1 = (const float*)d_in[3];
    const float* b1 = (const float*)d_in[4];
    const float* W2 = (const float*)d_in[5];
    const float* al2 = (const float*)d_in[6];
    const float* ar2 = (const float*)d_in[7];
    const float* b2 = (const float*)d_in[8];
    const float* W3 = (const float*)d_in[9];
    const float* al3 = (const float*)d_in[10];
    const float* ar3 = (const float*)d_in[11];
    const float* b3 = (const float*)d_in[12];
    const int* src = (const int*)d_in[13];
    const int* dst = (const int*)d_in[14];

    float* ws = (float*)d_ws;
    float* feat = ws;                          // N*64
    float* h1   = feat + (size_t)N * HF;       // N*64 (aliased by ebuf2 pre-layer1)
    float* h2   = h1 + (size_t)N * HF;         // N*64
    float* el   = h2 + (size_t)N * HF;         // N
    float* er   = el + N;                      // N
    int* deg    = (int*)(er + N);              // N
    int* cur    = deg + N;                     // N
    int* bsum   = cur + N;                     // 256
    int* gcur   = bsum + 256;                  // 256
    int* esrc   = gcur + 256;                  // E
    int2* ebuf2 = (int2*)h1;                   // E int2 (12.8MB of h1's 25.6MB)

    const int NB1024 = (N + 1023) / 1024;
    const int gEdge = (E + 255) / 256;
    const int gNode4 = (N + 3) / 4;
    const int gN256 = (N + 255) / 256;
    const int gTile = (N + 127) / 128;

    // ---- CSR build (same graph for all 3 layers) ----
    hipMemsetAsync(deg, 0, (size_t)N * 4, stream);
    k_hist<<<gEdge, 256, 0, stream>>>(dst, deg, E);
    k_scan1<<<NB1024, 256, 0, stream>>>(deg, cur, bsum, N);
    k_scan2<<<1, 128, 0, stream>>>(bsum, NB1024);
    k_scan3<<<gN256, 256, 0, stream>>>(cur, bsum, N);
    k_bucketinit<<<1, 256, 0, stream>>>(cur, gcur, N, E);
    k_bucket<<<KB_BLOCKS, 256, 0, stream>>>(src, dst, gcur, ebuf2, E);
    k_scatter2<<<gEdge, 256, 0, stream>>>(ebuf2, cur, esrc, E);

    float* out = (float*)d_out;

    // ---- layer 1 (K=128) ----
    gemm_tile<128><<<gTile, 256, 0, stream>>>(in_feat, W1, al1, ar1, feat, el, er, N);
    node_agg<<<gNode4, 256, 0, stream>>>(cur, deg, esrc, el, er, feat, b1, h1, N);

    // ---- layer 2 (K=64) ----
    gemm_tile<64><<<gTile, 256, 0, stream>>>(h1, W2, al2, ar2, feat, el, er, N);
    node_agg<<<gNode4, 256, 0, stream>>>(cur, deg, esrc, el, er, feat, b2, h2, N);

    // ---- layer 3 (K=64) ----
    gemm_tile<64><<<gTile, 256, 0, stream>>>(h2, W3, al3, ar3, feat, el, er, N);
    node_agg<<<gNode4, 256, 0, stream>>>(cur, deg, esrc, el, er, feat, b3, out, N);
}

// Round 10
// 342.954 us; speedup vs baseline: 5.4303x; 1.1994x over previous
//
#include <hip/hip_runtime.h>
#include <math.h>

#define NNODES 100000
#define NEDGES 1600000
#define HF 64
#define NBUCK_SHIFT 9
#define NBUCK 256                                // counter slots (power of 2)
#define NBUCK_USED ((NNODES + 511) >> 9)         // 196 buckets actually used
#define KC_BLOCKS 512
#define KB_BLOCKS 1024

// ======================= CSR build (bucket-based, no node-grain global atomics)
// pass 0: bucket counts via per-block LDS hist (few, low-contention atomics)
__global__ __launch_bounds__(256) void k_bcount(
    const int* __restrict__ dst, int* __restrict__ bcnt, int E)
{
    __shared__ int hist[NBUCK];
    const int tid = threadIdx.x;
    const int EPB = (E + KC_BLOCKS - 1) / KC_BLOCKS;
    const int e0 = blockIdx.x * EPB;
    const int e1 = min(E, e0 + EPB);
    hist[tid] = 0;
    __syncthreads();
    for (int i = e0 + tid; i < e1; i += 256)
        atomicAdd(&hist[dst[i] >> NBUCK_SHIFT], 1);
    __syncthreads();
    if (hist[tid]) atomicAdd(&bcnt[tid], hist[tid]);
}

// pass 0b: single-block scan of bucket counts -> bucket starts
__global__ __launch_bounds__(256) void k_bscan(
    const int* __restrict__ bcnt, int* __restrict__ gcur, int* __restrict__ bstart)
{
    __shared__ int s[256];
    const int tid = threadIdx.x;
    int own = bcnt[tid];
    s[tid] = own;
    __syncthreads();
    for (int off = 1; off < 256; off <<= 1) {
        int t = (tid >= off) ? s[tid - off] : 0;
        __syncthreads();
        s[tid] += t;
        __syncthreads();
    }
    int excl = s[tid] - own;
    gcur[tid] = excl;
    bstart[tid] = excl;
    if (tid == 255) bstart[256] = s[255];   // = E
}

// pass 1: partition edges into dst-buckets (locality-friendly writes)
__global__ __launch_bounds__(256) void k_bucket(
    const int* __restrict__ src, const int* __restrict__ dst,
    int* __restrict__ gcur, int2* __restrict__ ebuf2, int E)
{
    __shared__ int hist[NBUCK];
    const int tid = threadIdx.x;
    const int EPB = (E + KB_BLOCKS - 1) / KB_BLOCKS;
    const int e0 = blockIdx.x * EPB;
    const int e1 = min(E, e0 + EPB);

    hist[tid] = 0;
    __syncthreads();
    for (int i = e0 + tid; i < e1; i += 256)
        atomicAdd(&hist[dst[i] >> NBUCK_SHIFT], 1);
    __syncthreads();
    int cnt = hist[tid];
    int base = (cnt > 0) ? atomicAdd(&gcur[tid], cnt) : 0;
    __syncthreads();
    hist[tid] = base;
    __syncthreads();
    for (int i = e0 + tid; i < e1; i += 256) {
        int d = dst[i];
        int r = atomicAdd(&hist[d >> NBUCK_SHIFT], 1);
        ebuf2[r] = make_int2(src[i], d);
    }
}

// pass 2: per-bucket local CSR — LDS histogram + scan + scatter.
// writes deg/cur coalesced; esrc writes confined to the bucket's window.
__global__ __launch_bounds__(256) void k_local(
    const int2* __restrict__ ebuf2, const int* __restrict__ bstart,
    int* __restrict__ deg, int* __restrict__ cur, int* __restrict__ esrc)
{
    __shared__ int lhist[512];
    __shared__ int lcur[512];
    __shared__ int s[256];
    const int b = blockIdx.x;
    const int tid = threadIdx.x;
    const int e0 = bstart[b];
    const int e1 = bstart[b + 1];
    const int n0 = b << NBUCK_SHIFT;

    lhist[tid] = 0;
    lhist[tid + 256] = 0;
    __syncthreads();
    for (int i = e0 + tid; i < e1; i += 256)
        atomicAdd(&lhist[ebuf2[i].y - n0], 1);
    __syncthreads();

    int v0 = lhist[2 * tid], v1 = lhist[2 * tid + 1];
    int tsum = v0 + v1;
    s[tid] = tsum;
    __syncthreads();
    for (int off = 1; off < 256; off <<= 1) {
        int t = (tid >= off) ? s[tid - off] : 0;
        __syncthreads();
        s[tid] += t;
        __syncthreads();
    }
    int run = s[tid] - tsum;       // exclusive prefix of this thread's pair
    lcur[2 * tid] = run;
    lcur[2 * tid + 1] = run + v0;
    int node0 = n0 + 2 * tid;
    if (node0 < NNODES)     { deg[node0] = v0;     cur[node0] = e0 + run + v0; }
    if (node0 + 1 < NNODES) { deg[node0 + 1] = v1; cur[node0 + 1] = e0 + run + v0 + v1; }
    __syncthreads();

    for (int i = e0 + tid; i < e1; i += 256) {
        int2 e = ebuf2[i];
        int p = atomicAdd(&lcur[e.y - n0], 1);
        esrc[e0 + p] = e.x;
    }
}

// ======================= tiled GEMM: feat = x@W^T, el, er ================
template <int K>
__global__ __launch_bounds__(256) void gemm_tile(
    const float* __restrict__ x, const float* __restrict__ W,
    const float* __restrict__ al, const float* __restrict__ ar,
    float* __restrict__ feat, float* __restrict__ el, float* __restrict__ er,
    int n)
{
    constexpr int KS = 32;
    __shared__ float xs[KS][132];
    __shared__ float wt[KS][68];

    const int tid = threadIdx.x;
    const int tx = tid & 15;
    const int ty = tid >> 4;
    const int row0 = blockIdx.x * 128;

    float acc[8][4];
#pragma unroll
    for (int i = 0; i < 8; ++i)
#pragma unroll
        for (int j = 0; j < 4; ++j) acc[i][j] = 0.f;

    for (int ks = 0; ks < K; ks += KS) {
        if (ks) __syncthreads();
#pragma unroll
        for (int jj = 0; jj < 4; ++jj) {
            int j = tid + jj * 256;
            int r = j >> 3;
            int k4 = j & 7;
            int gr = row0 + r;
            float4 v = make_float4(0.f, 0.f, 0.f, 0.f);
            if (gr < n) v = *(const float4*)(x + (size_t)gr * K + ks + 4 * k4);
            xs[4 * k4 + 0][r] = v.x;
            xs[4 * k4 + 1][r] = v.y;
            xs[4 * k4 + 2][r] = v.z;
            xs[4 * k4 + 3][r] = v.w;
        }
#pragma unroll
        for (int jj = 0; jj < 2; ++jj) {
            int j = tid + jj * 256;
            int c = j >> 3;
            int k4 = j & 7;
            float4 v = *(const float4*)(W + (size_t)c * K + ks + 4 * k4);
            wt[4 * k4 + 0][c] = v.x;
            wt[4 * k4 + 1][c] = v.y;
            wt[4 * k4 + 2][c] = v.z;
            wt[4 * k4 + 3][c] = v.w;
        }
        __syncthreads();

#pragma unroll 8
        for (int k = 0; k < KS; ++k) {
            float4 a0 = *(const float4*)&xs[k][8 * ty + 0];
            float4 a1 = *(const float4*)&xs[k][8 * ty + 4];
            float4 b  = *(const float4*)&wt[k][4 * tx];
            float ar_[8] = {a0.x, a0.y, a0.z, a0.w, a1.x, a1.y, a1.z, a1.w};
            float bc[4] = {b.x, b.y, b.z, b.w};
#pragma unroll
            for (int i = 0; i < 8; ++i)
#pragma unroll
                for (int j = 0; j < 4; ++j)
                    acc[i][j] += ar_[i] * bc[j];
        }
    }

    const float4 ald = *(const float4*)(al + 4 * tx);
    const float4 ard = *(const float4*)(ar + 4 * tx);
#pragma unroll
    for (int i = 0; i < 8; ++i) {
        int row = row0 + 8 * ty + i;
        float pl = acc[i][0] * ald.x + acc[i][1] * ald.y +
                   acc[i][2] * ald.z + acc[i][3] * ald.w;
        float pr = acc[i][0] * ard.x + acc[i][1] * ard.y +
                   acc[i][2] * ard.z + acc[i][3] * ard.w;
#pragma unroll
        for (int off = 8; off >= 1; off >>= 1) {
            pl += __shfl_xor(pl, off);
            pr += __shfl_xor(pr, off);
        }
        if (row < n) {
            float4 st = make_float4(acc[i][0], acc[i][1], acc[i][2], acc[i][3]);
            *(float4*)(feat + (size_t)row * HF + 4 * tx) = st;
            if (tx == 0) { el[row] = pl; er[row] = pr; }
        }
    }
}

// ======================= fused per-node softmax-aggregate =================
__global__ __launch_bounds__(256) void node_agg(
    const int* __restrict__ cur, const int* __restrict__ deg,
    const int* __restrict__ esrc,
    const float* __restrict__ el, const float* __restrict__ er,
    const float* __restrict__ feat, const float* __restrict__ bias,
    float* __restrict__ out, int n)
{
    const int node = blockIdx.x * 4 + (threadIdx.x >> 6);
    if (node >= n) return;
    const int lane = threadIdx.x & 63;
    const int cx = lane & 15;
    const int lg = lane >> 4;

    const int dg = deg[node];

    if (dg == 0) {
        if (lane < 16) {
            float4 b4 = *(const float4*)(bias + 4 * cx);
            float4 o;
            o.x = fmaxf(b4.x, 0.f); o.y = fmaxf(b4.y, 0.f);
            o.z = fmaxf(b4.z, 0.f); o.w = fmaxf(b4.w, 0.f);
            *(float4*)(out + (size_t)node * HF + 4 * cx) = o;
        }
        return;
    }

    const int base = cur[node] - dg;
    const float erd = er[node];

    if (dg <= 32) {
        int sreg = 0;
        if (lane < dg) sreg = esrc[base + lane];
        float elv = 0.f;
        if (lane < dg) elv = el[sreg];

        int sj[8];
#pragma unroll
        for (int t = 0; t < 8; ++t) sj[t] = __shfl(sreg, lg + 4 * t);

        float4 f[8];
#pragma unroll
        for (int t = 0; t < 8; ++t)
            if (lg + 4 * t < dg)
                f[t] = *(const float4*)(feat + (size_t)sj[t] * HF + 4 * cx);

        float ereg = -INFINITY;
        if (lane < dg) {
            float e = elv + erd;
            ereg = (e >= 0.f) ? e : 0.2f * e;
        }
        float m = ereg;
#pragma unroll
        for (int off = 32; off >= 1; off >>= 1)
            m = fmaxf(m, __shfl_xor(m, off));
        float ee = __expf(ereg - m);
        float den = ee;
#pragma unroll
        for (int off = 32; off >= 1; off >>= 1)
            den += __shfl_xor(den, off);

        float4 c[4];
#pragma unroll
        for (int q = 0; q < 4; ++q) c[q] = make_float4(0.f, 0.f, 0.f, 0.f);
#pragma unroll
        for (int t = 0; t < 8; ++t) {
            float w = __shfl(ee, lg + 4 * t);
            if (lg + 4 * t < dg) {
                c[t & 3].x += w * f[t].x;
                c[t & 3].y += w * f[t].y;
                c[t & 3].z += w * f[t].z;
                c[t & 3].w += w * f[t].w;
            }
        }
        float4 acc;
        acc.x = (c[0].x + c[1].x) + (c[2].x + c[3].x);
        acc.y = (c[0].y + c[1].y) + (c[2].y + c[3].y);
        acc.z = (c[0].z + c[1].z) + (c[2].z + c[3].z);
        acc.w = (c[0].w + c[1].w) + (c[2].w + c[3].w);
#pragma unroll
        for (int off = 16; off <= 32; off <<= 1) {
            acc.x += __shfl_xor(acc.x, off);
            acc.y += __shfl_xor(acc.y, off);
            acc.z += __shfl_xor(acc.z, off);
            acc.w += __shfl_xor(acc.w, off);
        }
        if (lane < 16) {
            float inv = 1.f / den;
            float4 b4 = *(const float4*)(bias + 4 * cx);
            float4 o;
            o.x = fmaxf(acc.x * inv + b4.x, 0.f);
            o.y = fmaxf(acc.y * inv + b4.y, 0.f);
            o.z = fmaxf(acc.z * inv + b4.z, 0.f);
            o.w = fmaxf(acc.w * inv + b4.w, 0.f);
            *(float4*)(out + (size_t)node * HF + 4 * cx) = o;
        }
        return;
    }

    if (dg <= 64) {
        int sreg = 0;
        float ereg = -INFINITY;
        if (lane < dg) {
            sreg = esrc[base + lane];
            float e = el[sreg] + erd;
            ereg = (e >= 0.f) ? e : 0.2f * e;
        }
        float m = ereg;
#pragma unroll
        for (int off = 32; off >= 1; off >>= 1)
            m = fmaxf(m, __shfl_xor(m, off));
        float ee = __expf(ereg - m);
        float den = ee;
#pragma unroll
        for (int off = 32; off >= 1; off >>= 1)
            den += __shfl_xor(den, off);

        float4 c[4];
#pragma unroll
        for (int q = 0; q < 4; ++q) c[q] = make_float4(0.f, 0.f, 0.f, 0.f);
        for (int j0 = 0; j0 < dg; j0 += 16) {
#pragma unroll
            for (int q = 0; q < 4; ++q) {
                int jj = j0 + lg + 4 * q;
                int   s = __shfl(sreg, jj & 63);
                float w = __shfl(ee, jj & 63);
                if (jj < dg) {
                    float4 fv = *(const float4*)(feat + (size_t)s * HF + 4 * cx);
                    c[q].x += w * fv.x;
                    c[q].y += w * fv.y;
                    c[q].z += w * fv.z;
                    c[q].w += w * fv.w;
                }
            }
        }
        float4 acc;
        acc.x = (c[0].x + c[1].x) + (c[2].x + c[3].x);
        acc.y = (c[0].y + c[1].y) + (c[2].y + c[3].y);
        acc.z = (c[0].z + c[1].z) + (c[2].z + c[3].z);
        acc.w = (c[0].w + c[1].w) + (c[2].w + c[3].w);
#pragma unroll
        for (int off = 16; off <= 32; off <<= 1) {
            acc.x += __shfl_xor(acc.x, off);
            acc.y += __shfl_xor(acc.y, off);
            acc.z += __shfl_xor(acc.z, off);
            acc.w += __shfl_xor(acc.w, off);
        }
        if (lane < 16) {
            float inv = 1.f / den;
            float4 b4 = *(const float4*)(bias + 4 * cx);
            float4 o;
            o.x = fmaxf(acc.x * inv + b4.x, 0.f);
            o.y = fmaxf(acc.y * inv + b4.y, 0.f);
            o.z = fmaxf(acc.z * inv + b4.z, 0.f);
            o.w = fmaxf(acc.w * inv + b4.w, 0.f);
            *(float4*)(out + (size_t)node * HF + 4 * cx) = o;
        }
        return;
    }

    // slow path (deg > 64)
    float m = -INFINITY;
    for (int j = lane; j < dg; j += 64) {
        int s = esrc[base + j];
        float e = el[s] + erd;
        e = (e >= 0.f) ? e : 0.2f * e;
        m = fmaxf(m, e);
    }
#pragma unroll
    for (int off = 32; off >= 1; off >>= 1)
        m = fmaxf(m, __shfl_xor(m, off));

    float acc = 0.f, den = 0.f;
    for (int j = 0; j < dg; ++j) {
        int s = esrc[base + j];
        float e = el[s] + erd;
        e = (e >= 0.f) ? e : 0.2f * e;
        float ee = __expf(e - m);
        den += ee;
        acc += ee * feat[(size_t)s * HF + lane];
    }
    out[(size_t)node * HF + lane] = fmaxf(acc / den + bias[lane], 0.f);
}

extern "C" void kernel_launch(void* const* d_in, const int* in_sizes, int n_in,
                              void* d_out, int out_size, void* d_ws, size_t ws_size,
                              hipStream_t stream) {
    const int N = NNODES;
    const int E = NEDGES;

    const float* in_feat = (const float*)d_in[0];
    const float* W1 = (const float*)d_in[1];
    const float* al1 = (const float*)d_in[2];
    const float* ar1 = (const float*)d_in[3];
    const float* b1 = (const float*)d_in[4];
    const float* W2 = (const float*)d_in[5];
    const float* al2 = (const float*)d_in[6];
    const float* ar2 = (const float*)d_in[7];
    const float* b2 = (const float*)d_in[8];
    const float* W3 = (const float*)d_in[9];
    const float* al3 = (const float*)d_in[10];
    const float* ar3 = (const float*)d_in[11];
    const float* b3 = (const float*)d_in[12];
    const int* src = (const int*)d_in[13];
    const int* dst = (const int*)d_in[14];

    float* ws = (float*)d_ws;
    float* feat = ws;                          // N*64
    float* h1   = feat + (size_t)N * HF;       // N*64 (aliased by ebuf2 pre-layer1)
    float* h2   = h1 + (size_t)N * HF;         // N*64
    float* el   = h2 + (size_t)N * HF;         // N
    float* er   = el + N;                      // N
    int* deg    = (int*)(er + N);              // N
    int* cur    = deg + N;                     // N
    int* bcnt   = cur + N;                     // 256
    int* bstart = bcnt + 256;                  // 260 (257 used)
    int* gcur   = bstart + 260;                // 256
    int* esrc   = gcur + 256;                  // E
    int2* ebuf2 = (int2*)h1;                   // E int2 (12.8MB of h1's 25.6MB)

    const int gEdge = (E + 255) / 256;
    const int gNode4 = (N + 3) / 4;
    const int gTile = (N + 127) / 128;
    (void)gEdge;

    // ---- CSR build (bucket-based; same graph for all 3 layers) ----
    hipMemsetAsync(bcnt, 0, NBUCK * 4, stream);
    k_bcount<<<KC_BLOCKS, 256, 0, stream>>>(dst, bcnt, E);
    k_bscan<<<1, 256, 0, stream>>>(bcnt, gcur, bstart);
    k_bucket<<<KB_BLOCKS, 256, 0, stream>>>(src, dst, gcur, ebuf2, E);
    k_local<<<NBUCK_USED, 256, 0, stream>>>(ebuf2, bstart, deg, cur, esrc);

    float* out = (float*)d_out;

    // ---- layer 1 (K=128) ----
    gemm_tile<128><<<gTile, 256, 0, stream>>>(in_feat, W1, al1, ar1, feat, el, er, N);
    node_agg<<<gNode4, 256, 0, stream>>>(cur, deg, esrc, el, er, feat, b1, h1, N);

    // ---- layer 2 (K=64) ----
    gemm_tile<64><<<gTile, 256, 0, stream>>>(h1, W2, al2, ar2, feat, el, er, N);
    node_agg<<<gNode4, 256, 0, stream>>>(cur, deg, esrc, el, er, feat, b2, h2, N);

    // ---- layer 3 (K=64) ----
    gemm_tile<64><<<gTile, 256, 0, stream>>>(h2, W3, al3, ar3, feat, el, er, N);
    node_agg<<<gNode4, 256, 0, stream>>>(cur, deg, esrc, el, er, feat, b3, out, N);
}